// Round 2
// 349.526 us; speedup vs baseline: 1.5180x; 1.5180x over previous
//
#include <hip/hip_runtime.h>
#include <math.h>

namespace {

constexpr int Bsz = 8192;
constexpr int Fsz = 256;

// ---------------- compile-time Clifford algebra tables (Cl(3,0)) ----------------
struct Tables {
  int   jidx[64];
  float sgn[64];
  int   path[64];
  int   gr[8];
};

constexpr int cpopc(int v) { int c = 0; while (v) { c += v & 1; v >>= 1; } return c; }

constexpr Tables make_tables() {
  Tables t{};
  constexpr int MASKS[8] = {0, 1, 2, 4, 3, 5, 6, 7};
  int inv[8] = {};
  for (int i = 0; i < 8; ++i) inv[MASKS[i]] = i;
  int grade[8] = {};
  for (int i = 0; i < 8; ++i) { grade[i] = cpopc(MASKS[i]); t.gr[i] = grade[i]; }
  int pidx[4][4][4] = {};
  for (int a = 0; a < 4; ++a)
    for (int b = 0; b < 4; ++b)
      for (int c = 0; c < 4; ++c) pidx[a][b][c] = -1;
  int np = 0;
  for (int gi = 0; gi < 4; ++gi)
    for (int gj = 0; gj < 4; ++gj)
      for (int gk = 0; gk < 4; ++gk) {
        bool any = false;
        for (int i = 0; i < 8; ++i)
          for (int k = 0; k < 8; ++k)
            if (grade[i] == gi && grade[k] == gk && cpopc(MASKS[i] ^ MASKS[k]) == gj) any = true;
        if (any) pidx[gi][gj][gk] = np++;
      }
  for (int i = 0; i < 8; ++i)
    for (int k = 0; k < 8; ++k) {
      const int mi = MASKS[i], mk = MASKS[k];
      int s = 0, aa = mi >> 1;
      while (aa) { s += cpopc(aa & mk); aa >>= 1; }
      t.jidx[i * 8 + k] = inv[mi ^ mk];
      t.sgn[i * 8 + k]  = (s & 1) ? -1.0f : 1.0f;
      t.path[i * 8 + k] = pidx[grade[i]][cpopc(mi ^ mk)][grade[k]];
    }
  return t;
}

typedef __attribute__((ext_vector_type(8))) short bf16x8;   // 8 bf16 = 4 VGPRs
typedef __attribute__((ext_vector_type(4))) float f32x4;    // MFMA accumulator

struct f8 { float v[8]; };

__device__ inline f8 ld8(const float* p) {
  f8 r;
  float4 a = *(const float4*)p;
  float4 b = *(const float4*)(p + 4);
  r.v[0] = a.x; r.v[1] = a.y; r.v[2] = a.z; r.v[3] = a.w;
  r.v[4] = b.x; r.v[5] = b.y; r.v[6] = b.z; r.v[7] = b.w;
  return r;
}

__device__ inline unsigned short f2bf(float f) {   // RNE fp32 -> bf16
  unsigned int u = __float_as_uint(f);
  unsigned int r = ((u >> 16) & 1u) + 0x7fffu;
  return (unsigned short)((u + r) >> 16);
}
__device__ inline float bf2f(unsigned short h) { return __uint_as_float(((unsigned int)h) << 16); }

// ===================== prep kernels: split fp32 into bf16 hi/lo ================

// x [B,F,8] fp32 -> xh/xl [8][B][F] bf16 (blade-major planes)
__global__ __launch_bounds__(256) void prep_x(
    const float* __restrict__ x, unsigned short* __restrict__ xh,
    unsigned short* __restrict__ xl)
{
  const int t = blockIdx.x * 256 + threadIdx.x;     // t < 8192*64
  const int b = t >> 6;
  const int m0 = (t & 63) << 2;                     // 4 consecutive m
  const float* src = x + (((size_t)b << 8) + m0) * 8;   // 32 floats
  float4 v[8];
  #pragma unroll
  for (int j = 0; j < 8; ++j) v[j] = ((const float4*)src)[j];
  const float* vf = (const float*)v;
  #pragma unroll
  for (int i = 0; i < 8; ++i) {
    ushort4 hv, lv;
    float f0 = vf[0 * 8 + i], f1 = vf[1 * 8 + i], f2 = vf[2 * 8 + i], f3 = vf[3 * 8 + i];
    hv.x = f2bf(f0); hv.y = f2bf(f1); hv.z = f2bf(f2); hv.w = f2bf(f3);
    lv.x = f2bf(f0 - bf2f(hv.x)); lv.y = f2bf(f1 - bf2f(hv.y));
    lv.z = f2bf(f2 - bf2f(hv.z)); lv.w = f2bf(f3 - bf2f(hv.w));
    const size_t o = ((size_t)i << 21) + ((size_t)b << 8) + m0;
    *(ushort4*)(xh + o) = hv;
    *(ushort4*)(xl + o) = lv;
  }
}

// wl/wr [F,F,4] fp32 -> wh/wlo [2*4][F(n)][F(m)] bf16 (per side,grade planes)
__global__ __launch_bounds__(256) void prep_w(
    const float* __restrict__ wl, const float* __restrict__ wr,
    unsigned short* __restrict__ wh, unsigned short* __restrict__ wlo)
{
  const int t = blockIdx.x * 256 + threadIdx.x;     // t < 131072
  const int sg = t >> 14;                           // 0..7: s = sg>>2, g = sg&3
  const int s = sg >> 2, g = sg & 3;
  const int rem = t & 16383;
  const int n = rem >> 6;
  const int m0 = (rem & 63) << 2;
  const float* w = s ? wr : wl;
  ushort4 hv, lv;
  float f0 = w[(((size_t)n << 8) + m0 + 0) * 4 + g];
  float f1 = w[(((size_t)n << 8) + m0 + 1) * 4 + g];
  float f2 = w[(((size_t)n << 8) + m0 + 2) * 4 + g];
  float f3 = w[(((size_t)n << 8) + m0 + 3) * 4 + g];
  hv.x = f2bf(f0); hv.y = f2bf(f1); hv.z = f2bf(f2); hv.w = f2bf(f3);
  lv.x = f2bf(f0 - bf2f(hv.x)); lv.y = f2bf(f1 - bf2f(hv.y));
  lv.z = f2bf(f2 - bf2f(hv.z)); lv.w = f2bf(f3 - bf2f(hv.w));
  const size_t o = ((size_t)sg << 16) + ((size_t)n << 8) + m0;
  *(ushort4*)(wh + o) = hv;
  *(ushort4*)(wlo + o) = lv;
}

// ============ MFMA kernel: LDS-free split-bf16 GEMM + fused epilogue ===========
// block = 512 threads = 8 waves; wave = one blade; tile 32b x 32n (both sides).
// A and B fragments for mfma_f32_16x16x32_bf16 are 8 contiguous k-elements in
// the blade-major planes -> loaded DIRECTLY global->register (dwordx4).
// No LDS staging, no K-loop barriers, no cross-wave coupling until the
// epilogue exchange. 3-pass split-bf16 (hi*hi + hi*lo + lo*hi) in fp32 acc.
__global__ __launch_bounds__(512) void sgp_mfma(
    const float* __restrict__ x,    // [B,F,8]
    const float* __restrict__ blft, // [1,F,1]
    const float* __restrict__ an,   // [F,4]
    const float* __restrict__ wgp,  // [F,20]
    const unsigned short* __restrict__ xh, const unsigned short* __restrict__ xl,
    const unsigned short* __restrict__ wh, const unsigned short* __restrict__ wlo,
    float* __restrict__ out)        // [B,F,8]
{
  constexpr Tables T = make_tables();

  __shared__ __align__(16) float ex[16 * 32 * 17];   // epilogue exchange, 34816 B

  const int tid = threadIdx.x;
  const int wid = tid >> 6;              // wave id = blade id
  const int lane = tid & 63;
  const int bb = blockIdx.y << 5;        // 32 b-rows
  const int nn = blockIdx.x << 5;        // 32 n-cols
  const int gI = T.gr[wid];

  const int l15 = lane & 15;
  const int klane = (lane >> 4) << 3;    // k-subchunk base for this lane (0,8,16,24)

  // --- per-lane global fragment base pointers (ushort elements) ---
  // A: x-plane[wid], rows bb+l15 and bb+16+l15
  const unsigned short* aH0 = xh + ((size_t)wid << 21) + ((size_t)(bb + l15) << 8) + klane;
  const unsigned short* aH1 = xh + ((size_t)wid << 21) + ((size_t)(bb + 16 + l15) << 8) + klane;
  const unsigned short* aL0 = xl + ((size_t)wid << 21) + ((size_t)(bb + l15) << 8) + klane;
  const unsigned short* aL1 = xl + ((size_t)wid << 21) + ((size_t)(bb + 16 + l15) << 8) + klane;
  // B: planes gI (left) and 4+gI (right), rows nn+l15 and nn+16+l15
  const unsigned short* bH[4];
  const unsigned short* bL[4];
  #pragma unroll
  for (int ns = 0; ns < 4; ++ns) {
    const int plane = ((ns >> 1) << 2) + gI;       // side*4 + grade
    const int row = nn + ((ns & 1) << 4) + l15;
    bH[ns] = wh  + ((size_t)plane << 16) + ((size_t)row << 8) + klane;
    bL[ns] = wlo + ((size_t)plane << 16) + ((size_t)row << 8) + klane;
  }

  f32x4 acc[2][4];
  #pragma unroll
  for (int a = 0; a < 2; ++a)
    #pragma unroll
    for (int c = 0; c < 4; ++c) acc[a][c] = (f32x4)(0.0f);

  for (int kt = 0; kt < 8; ++kt) {
    const int ko = kt * 32;
    bf16x8 Ah0 = *(const bf16x8*)(aH0 + ko);
    bf16x8 Ah1 = *(const bf16x8*)(aH1 + ko);
    bf16x8 Al0 = *(const bf16x8*)(aL0 + ko);
    bf16x8 Al1 = *(const bf16x8*)(aL1 + ko);
    #pragma unroll
    for (int ns = 0; ns < 4; ++ns) {
      bf16x8 Bh = *(const bf16x8*)(bH[ns] + ko);
      bf16x8 Bl = *(const bf16x8*)(bL[ns] + ko);
      acc[0][ns] = __builtin_amdgcn_mfma_f32_16x16x32_bf16(Ah0, Bh, acc[0][ns], 0, 0, 0);
      acc[1][ns] = __builtin_amdgcn_mfma_f32_16x16x32_bf16(Ah1, Bh, acc[1][ns], 0, 0, 0);
      acc[0][ns] = __builtin_amdgcn_mfma_f32_16x16x32_bf16(Ah0, Bl, acc[0][ns], 0, 0, 0);
      acc[1][ns] = __builtin_amdgcn_mfma_f32_16x16x32_bf16(Ah1, Bl, acc[1][ns], 0, 0, 0);
      acc[0][ns] = __builtin_amdgcn_mfma_f32_16x16x32_bf16(Al0, Bh, acc[0][ns], 0, 0, 0);
      acc[1][ns] = __builtin_amdgcn_mfma_f32_16x16x32_bf16(Al1, Bh, acc[1][ns], 0, 0, 0);
    }
  }

  // ================= fused epilogue: exchange blades via LDS, norm + gp =========
  const float inv_sqrt2 = 0.7071067811865476f;

  #pragma unroll
  for (int c = 0; c < 2; ++c) {          // two 16-row b-chunks (== acc first index)
    if (c) __syncthreads();
    // D layout: col(n) = lane&15, row(m) = (lane>>4)*4 + reg   [verified m89/m91]
    #pragma unroll
    for (int ns = 0; ns < 4; ++ns) {
      const int n = ((ns & 1) << 4) + l15;
      const int so = ((ns >> 1) << 3) + wid;   // side*8 + blade
      #pragma unroll
      for (int r = 0; r < 4; ++r) {
        const int row = ((lane >> 4) << 2) + r;
        ex[(row * 32 + n) * 17 + so] = acc[c][ns][r];
      }
    }
    __syncthreads();

    // read + gp: one (b,n) pair per thread
    const int prow = tid >> 5, pn = tid & 31;
    const float* e = &ex[(prow * 32 + pn) * 17];
    float L[8], R[8];
    #pragma unroll
    for (int i = 0; i < 8; ++i) { L[i] = e[i]; R[i] = e[8 + i]; }

    const int b  = bb + (c << 4) + prow;
    const int ng = nn + pn;

    float4 anv = *(const float4*)(an + (size_t)ng * 4);
    const float bias = blft[ng];
    float wd[20];
    #pragma unroll
    for (int q = 0; q < 5; ++q) {
      float4 w4 = *(const float4*)(wgp + (size_t)ng * 20 + q * 4);
      wd[q * 4 + 0] = w4.x; wd[q * 4 + 1] = w4.y;
      wd[q * 4 + 2] = w4.z; wd[q * 4 + 3] = w4.w;
    }
    float sgm[4];
    sgm[0] = 1.f / (1.f + expf(-anv.x));
    sgm[1] = 1.f / (1.f + expf(-anv.y));
    sgm[2] = 1.f / (1.f + expf(-anv.z));
    sgm[3] = 1.f / (1.f + expf(-anv.w));

    float q0 = R[0] * R[0];
    float q1 = R[1] * R[1] + R[2] * R[2] + R[3] * R[3];
    float q2 = R[4] * R[4] + R[5] * R[5] + R[6] * R[6];
    float q3 = R[7] * R[7];
    float nrm[4];
    nrm[0] = sqrtf(sqrtf(q0 * q0 + 1e-16f));
    nrm[1] = sqrtf(sqrtf(q1 * q1 + 1e-16f));
    nrm[2] = sqrtf(sqrtf(q2 * q2 + 1e-16f));
    nrm[3] = sqrtf(sqrtf(q3 * q3 + 1e-16f));
    float invn[4];
    #pragma unroll
    for (int g = 0; g < 4; ++g)
      invn[g] = 1.0f / (sgm[g] * (nrm[g] - 1.0f) + 1.0f + 1e-6f);

    float xr[8];
    #pragma unroll
    for (int i = 0; i < 8; ++i) xr[i] = R[i] * invn[T.gr[i]];

    f8 xv = ld8(x + (((size_t)b << 8) + ng) * 8);

    float gp[8] = {0, 0, 0, 0, 0, 0, 0, 0};
    #pragma unroll
    for (int i = 0; i < 8; ++i) {
      #pragma unroll
      for (int k = 0; k < 8; ++k) {
        const int p = i * 8 + k;
        gp[T.jidx[p]] += T.sgn[p] * wd[T.path[p]] * xv.v[i] * xr[k];
      }
    }

    float o[8];
    #pragma unroll
    for (int i = 0; i < 8; ++i)
      o[i] = (L[i] + gp[i] + (i == 0 ? bias : 0.f)) * inv_sqrt2;

    float4* dst = (float4*)(out + (((size_t)b << 8) + ng) * 8);
    dst[0] = make_float4(o[0], o[1], o[2], o[3]);
    dst[1] = make_float4(o[4], o[5], o[6], o[7]);
  }
}

// ===================== legacy fallback (verified, 530us) ======================

constexpr int BT = 32;
constexpr int NT = 32;
constexpr int MT = 16;
constexpr int RS = 12;
constexpr int MS = BT * RS + 4;

__global__ __launch_bounds__(256) void sgp_fused(
    const float* __restrict__ x,
    const float* __restrict__ wl,
    const float* __restrict__ blft,
    const float* __restrict__ wr,
    const float* __restrict__ an,
    const float* __restrict__ wgp,
    float* __restrict__ out)
{
  constexpr Tables T = make_tables();

  __shared__ float xs[MT * MS];
  __shared__ float wsh[MT * MS];

  const int tid = threadIdx.x;
  const int tx = tid & 15;
  const int ty = tid >> 4;
  const int bb = blockIdx.x * BT;
  const int nn = blockIdx.y * NT;

  const int rl = tid >> 4;
  const int cm = tid & 15;

  float accL[2][2][8];
  float accR[2][2][8];
  #pragma unroll
  for (int a = 0; a < 2; ++a)
    #pragma unroll
    for (int c = 0; c < 2; ++c)
      #pragma unroll
      for (int i = 0; i < 8; ++i) { accL[a][c][i] = 0.f; accR[a][c][i] = 0.f; }

  for (int mm = 0; mm < Fsz; mm += MT) {
    {
      const float* g0 = x + (((size_t)(bb + rl)) * Fsz + (mm + cm)) * 8;
      const float* g1 = x + (((size_t)(bb + rl + 16)) * Fsz + (mm + cm)) * 8;
      float4 a0 = ((const float4*)g0)[0];
      float4 a1 = ((const float4*)g0)[1];
      float4 b0 = ((const float4*)g1)[0];
      float4 b1 = ((const float4*)g1)[1];
      *(float4*)&xs[cm * MS + rl * RS + 0] = a0;
      *(float4*)&xs[cm * MS + rl * RS + 4] = a1;
      *(float4*)&xs[cm * MS + (rl + 16) * RS + 0] = b0;
      *(float4*)&xs[cm * MS + (rl + 16) * RS + 4] = b1;
      float4 l0 = *(const float4*)(wl + (((size_t)(nn + rl)) * Fsz + (mm + cm)) * 4);
      float4 l1 = *(const float4*)(wl + (((size_t)(nn + rl + 16)) * Fsz + (mm + cm)) * 4);
      float4 r0 = *(const float4*)(wr + (((size_t)(nn + rl)) * Fsz + (mm + cm)) * 4);
      float4 r1 = *(const float4*)(wr + (((size_t)(nn + rl + 16)) * Fsz + (mm + cm)) * 4);
      *(float4*)&wsh[cm * MS + rl * RS + 0] = l0;
      *(float4*)&wsh[cm * MS + rl * RS + 4] = r0;
      *(float4*)&wsh[cm * MS + (rl + 16) * RS + 0] = l1;
      *(float4*)&wsh[cm * MS + (rl + 16) * RS + 4] = r1;
    }
    __syncthreads();

    #pragma unroll
    for (int m = 0; m < MT; ++m) {
      f8 xf0 = ld8(&xs[m * MS + ty * RS]);
      f8 xf1 = ld8(&xs[m * MS + (ty + 16) * RS]);
      f8 wv0 = ld8(&wsh[m * MS + tx * RS]);
      f8 wv1 = ld8(&wsh[m * MS + (tx + 16) * RS]);

      #pragma unroll
      for (int i = 0; i < 8; ++i) {
        const int g = T.gr[i];
        accL[0][0][i] += xf0.v[i] * wv0.v[g];
        accR[0][0][i] += xf0.v[i] * wv0.v[4 + g];
        accL[0][1][i] += xf0.v[i] * wv1.v[g];
        accR[0][1][i] += xf0.v[i] * wv1.v[4 + g];
        accL[1][0][i] += xf1.v[i] * wv0.v[g];
        accR[1][0][i] += xf1.v[i] * wv0.v[4 + g];
        accL[1][1][i] += xf1.v[i] * wv1.v[g];
        accR[1][1][i] += xf1.v[i] * wv1.v[4 + g];
      }
    }
    __syncthreads();
  }

  const float inv_sqrt2 = 0.7071067811865476f;

  #pragma unroll
  for (int c = 0; c < 2; ++c) {
    const int n = nn + tx + c * 16;
    float4 anv = *(const float4*)(an + (size_t)n * 4);
    const float bias = blft[n];
    float wd[20];
    #pragma unroll
    for (int q = 0; q < 5; ++q) {
      float4 w4 = *(const float4*)(wgp + (size_t)n * 20 + q * 4);
      wd[q * 4 + 0] = w4.x; wd[q * 4 + 1] = w4.y;
      wd[q * 4 + 2] = w4.z; wd[q * 4 + 3] = w4.w;
    }
    float sg[4];
    sg[0] = 1.f / (1.f + expf(-anv.x));
    sg[1] = 1.f / (1.f + expf(-anv.y));
    sg[2] = 1.f / (1.f + expf(-anv.z));
    sg[3] = 1.f / (1.f + expf(-anv.w));

    #pragma unroll
    for (int a = 0; a < 2; ++a) {
      const int b = bb + ty + a * 16;
      const float* r = accR[a][c];

      float q0 = r[0] * r[0];
      float q1 = r[1] * r[1] + r[2] * r[2] + r[3] * r[3];
      float q2 = r[4] * r[4] + r[5] * r[5] + r[6] * r[6];
      float q3 = r[7] * r[7];
      float nrm[4];
      nrm[0] = sqrtf(sqrtf(q0 * q0 + 1e-16f));
      nrm[1] = sqrtf(sqrtf(q1 * q1 + 1e-16f));
      nrm[2] = sqrtf(sqrtf(q2 * q2 + 1e-16f));
      nrm[3] = sqrtf(sqrtf(q3 * q3 + 1e-16f));
      float invn[4];
      #pragma unroll
      for (int g = 0; g < 4; ++g)
        invn[g] = 1.0f / (sg[g] * (nrm[g] - 1.0f) + 1.0f + 1e-6f);

      float xr[8];
      #pragma unroll
      for (int i = 0; i < 8; ++i) xr[i] = r[i] * invn[T.gr[i]];

      f8 xv = ld8(x + (((size_t)b) * Fsz + n) * 8);

      float gp[8] = {0, 0, 0, 0, 0, 0, 0, 0};
      #pragma unroll
      for (int i = 0; i < 8; ++i) {
        #pragma unroll
        for (int k = 0; k < 8; ++k) {
          const int p = i * 8 + k;
          gp[T.jidx[p]] += T.sgn[p] * wd[T.path[p]] * xv.v[i] * xr[k];
        }
      }

      float o[8];
      #pragma unroll
      for (int i = 0; i < 8; ++i)
        o[i] = (accL[a][c][i] + gp[i] + (i == 0 ? bias : 0.f)) * inv_sqrt2;

      float4* dst = (float4*)(out + (((size_t)b) * Fsz + n) * 8);
      dst[0] = make_float4(o[0], o[1], o[2], o[3]);
      dst[1] = make_float4(o[4], o[5], o[6], o[7]);
    }
  }
}

}  // namespace

extern "C" void kernel_launch(void* const* d_in, const int* in_sizes, int n_in,
                              void* d_out, int out_size, void* d_ws, size_t ws_size,
                              hipStream_t stream) {
  const float* x   = (const float*)d_in[0];
  const float* wl  = (const float*)d_in[1];
  const float* bl  = (const float*)d_in[2];
  const float* wr  = (const float*)d_in[3];
  const float* an  = (const float*)d_in[4];
  const float* wgp = (const float*)d_in[5];
  float* out = (float*)d_out;

  // workspace layout (ushort elements):
  //   xh [8][8192][256], xl same, wh [8][256][256], wlo same
  const size_t NXE = (size_t)8 * Bsz * Fsz;      // 16,777,216
  const size_t NWE = (size_t)8 * Fsz * Fsz;      //    524,288
  const size_t need = (2 * NXE + 2 * NWE) * sizeof(unsigned short);  // 69,206,016 B

  if (d_ws != nullptr && ws_size >= need) {
    unsigned short* xh  = (unsigned short*)d_ws;
    unsigned short* xl  = xh + NXE;
    unsigned short* wh  = xl + NXE;
    unsigned short* wlo = wh + NWE;

    prep_x<<<dim3(2048), dim3(256), 0, stream>>>(x, xh, xl);
    prep_w<<<dim3(512), dim3(256), 0, stream>>>(wl, wr, wh, wlo);
    sgp_mfma<<<dim3(Fsz / 32, Bsz / 32), dim3(512), 0, stream>>>(
        x, bl, an, wgp, xh, xl, wh, wlo, out);
  } else {
    // fallback: verified fp32 VALU kernel
    dim3 grid(Bsz / BT, Fsz / NT);
    sgp_fused<<<grid, dim3(256), 0, stream>>>(x, wl, bl, wr, an, wgp, out);
  }
}

// Round 3
// 347.229 us; speedup vs baseline: 1.5281x; 1.0066x over previous
//
#include <hip/hip_runtime.h>
#include <math.h>

namespace {

constexpr int Bsz = 8192;
constexpr int Fsz = 256;

// ---------------- compile-time Clifford algebra tables (Cl(3,0)) ----------------
struct Tables {
  int   jidx[64];
  float sgn[64];
  int   path[64];
  int   gr[8];
};

constexpr int cpopc(int v) { int c = 0; while (v) { c += v & 1; v >>= 1; } return c; }

constexpr Tables make_tables() {
  Tables t{};
  constexpr int MASKS[8] = {0, 1, 2, 4, 3, 5, 6, 7};
  int inv[8] = {};
  for (int i = 0; i < 8; ++i) inv[MASKS[i]] = i;
  int grade[8] = {};
  for (int i = 0; i < 8; ++i) { grade[i] = cpopc(MASKS[i]); t.gr[i] = grade[i]; }
  int pidx[4][4][4] = {};
  for (int a = 0; a < 4; ++a)
    for (int b = 0; b < 4; ++b)
      for (int c = 0; c < 4; ++c) pidx[a][b][c] = -1;
  int np = 0;
  for (int gi = 0; gi < 4; ++gi)
    for (int gj = 0; gj < 4; ++gj)
      for (int gk = 0; gk < 4; ++gk) {
        bool any = false;
        for (int i = 0; i < 8; ++i)
          for (int k = 0; k < 8; ++k)
            if (grade[i] == gi && grade[k] == gk && cpopc(MASKS[i] ^ MASKS[k]) == gj) any = true;
        if (any) pidx[gi][gj][gk] = np++;
      }
  for (int i = 0; i < 8; ++i)
    for (int k = 0; k < 8; ++k) {
      const int mi = MASKS[i], mk = MASKS[k];
      int s = 0, aa = mi >> 1;
      while (aa) { s += cpopc(aa & mk); aa >>= 1; }
      t.jidx[i * 8 + k] = inv[mi ^ mk];
      t.sgn[i * 8 + k]  = (s & 1) ? -1.0f : 1.0f;
      t.path[i * 8 + k] = pidx[grade[i]][cpopc(mi ^ mk)][grade[k]];
    }
  return t;
}

typedef __attribute__((ext_vector_type(8))) short bf16x8;   // 8 bf16 = 4 VGPRs
typedef __attribute__((ext_vector_type(4))) float f32x4;    // MFMA accumulator

struct f8 { float v[8]; };

__device__ inline f8 ld8(const float* p) {
  f8 r;
  float4 a = *(const float4*)p;
  float4 b = *(const float4*)(p + 4);
  r.v[0] = a.x; r.v[1] = a.y; r.v[2] = a.z; r.v[3] = a.w;
  r.v[4] = b.x; r.v[5] = b.y; r.v[6] = b.z; r.v[7] = b.w;
  return r;
}

__device__ inline unsigned short f2bf(float f) {   // RNE fp32 -> bf16
  unsigned int u = __float_as_uint(f);
  unsigned int r = ((u >> 16) & 1u) + 0x7fffu;
  return (unsigned short)((u + r) >> 16);
}
__device__ inline float bf2f(unsigned short h) { return __uint_as_float(((unsigned int)h) << 16); }

// ===================== prep kernel: split fp32 into bf16 hi/lo =================
// blocks [0,1024): x [B,F,8] -> xh/xl [8][B][F]   (8 m-values per thread, 16B stores)
// blocks [1024,1536): wl/wr [F,F,4] -> wh/wlo [2*4][F(n)][F(m)]
__global__ __launch_bounds__(256) void prep_all(
    const float* __restrict__ x, const float* __restrict__ wl,
    const float* __restrict__ wr,
    unsigned short* __restrict__ xh, unsigned short* __restrict__ xl,
    unsigned short* __restrict__ wh, unsigned short* __restrict__ wlo)
{
  const int blk = blockIdx.x;
  if (blk < 1024) {
    const int t = blk * 256 + threadIdx.x;          // t < 262144
    const int b = t >> 5;
    const int m0 = (t & 31) << 3;                   // 8 consecutive m
    const float* src = x + (((size_t)b << 8) + m0) * 8;   // 64 floats
    float4 v[16];
    #pragma unroll
    for (int j = 0; j < 16; ++j) v[j] = ((const float4*)src)[j];
    const float* vf = (const float*)v;
    #pragma unroll
    for (int i = 0; i < 8; ++i) {
      unsigned int hw[4], lw[4];
      #pragma unroll
      for (int p = 0; p < 4; ++p) {
        float fa = vf[(2 * p) * 8 + i], fb = vf[(2 * p + 1) * 8 + i];
        unsigned short ha = f2bf(fa), hb = f2bf(fb);
        unsigned short la = f2bf(fa - bf2f(ha)), lb = f2bf(fb - bf2f(hb));
        hw[p] = (unsigned int)ha | ((unsigned int)hb << 16);
        lw[p] = (unsigned int)la | ((unsigned int)lb << 16);
      }
      const size_t o = ((size_t)i << 21) + ((size_t)b << 8) + m0;
      *(uint4*)(xh + o) = make_uint4(hw[0], hw[1], hw[2], hw[3]);
      *(uint4*)(xl + o) = make_uint4(lw[0], lw[1], lw[2], lw[3]);
    }
  } else {
    const int t = (blk - 1024) * 256 + threadIdx.x;  // t < 131072
    const int sg = t >> 14;                          // 0..7: s = sg>>2, g = sg&3
    const int s = sg >> 2, g = sg & 3;
    const int rem = t & 16383;
    const int n = rem >> 6;
    const int m0 = (rem & 63) << 2;
    const float* w = s ? wr : wl;
    ushort4 hv, lv;
    float f0 = w[(((size_t)n << 8) + m0 + 0) * 4 + g];
    float f1 = w[(((size_t)n << 8) + m0 + 1) * 4 + g];
    float f2 = w[(((size_t)n << 8) + m0 + 2) * 4 + g];
    float f3 = w[(((size_t)n << 8) + m0 + 3) * 4 + g];
    hv.x = f2bf(f0); hv.y = f2bf(f1); hv.z = f2bf(f2); hv.w = f2bf(f3);
    lv.x = f2bf(f0 - bf2f(hv.x)); lv.y = f2bf(f1 - bf2f(hv.y));
    lv.z = f2bf(f2 - bf2f(hv.z)); lv.w = f2bf(f3 - bf2f(hv.w));
    const size_t o = ((size_t)sg << 16) + ((size_t)n << 8) + m0;
    *(ushort4*)(wh + o) = hv;
    *(ushort4*)(wlo + o) = lv;
  }
}

// ============ MFMA kernel: LDS-free split-bf16 GEMM + fused epilogue ===========
// 1-D grid 2048, XCD-swizzled: XCD k owns b-tiles [32k,32k+32); the 8 n-tiles of
// one b-tile are adjacent in that XCD's queue -> A tile served from its L2.
// K-loop: fully unrolled, depth-1 register double-buffer (two fragment sets).
struct KF {
  bf16x8 Ah0, Ah1, Al0, Al1;
  bf16x8 Bh0, Bh1, Bh2, Bh3;
  bf16x8 Bl0, Bl1, Bl2, Bl3;
};

struct Ptrs {
  const unsigned short *aH0, *aH1, *aL0, *aL1;
  const unsigned short *bH0, *bH1, *bH2, *bH3;
  const unsigned short *bL0, *bL1, *bL2, *bL3;
};

__device__ __forceinline__ void loadk(KF& f, const Ptrs& p, int ko) {
  f.Ah0 = *(const bf16x8*)(p.aH0 + ko); f.Ah1 = *(const bf16x8*)(p.aH1 + ko);
  f.Al0 = *(const bf16x8*)(p.aL0 + ko); f.Al1 = *(const bf16x8*)(p.aL1 + ko);
  f.Bh0 = *(const bf16x8*)(p.bH0 + ko); f.Bh1 = *(const bf16x8*)(p.bH1 + ko);
  f.Bh2 = *(const bf16x8*)(p.bH2 + ko); f.Bh3 = *(const bf16x8*)(p.bH3 + ko);
  f.Bl0 = *(const bf16x8*)(p.bL0 + ko); f.Bl1 = *(const bf16x8*)(p.bL1 + ko);
  f.Bl2 = *(const bf16x8*)(p.bL2 + ko); f.Bl3 = *(const bf16x8*)(p.bL3 + ko);
}

__device__ __forceinline__ void mfmak(const KF& f, f32x4 (&acc)[2][4]) {
#define MF1(NS, BH, BL) \
  acc[0][NS] = __builtin_amdgcn_mfma_f32_16x16x32_bf16(f.Ah0, f.BH, acc[0][NS], 0, 0, 0); \
  acc[1][NS] = __builtin_amdgcn_mfma_f32_16x16x32_bf16(f.Ah1, f.BH, acc[1][NS], 0, 0, 0); \
  acc[0][NS] = __builtin_amdgcn_mfma_f32_16x16x32_bf16(f.Ah0, f.BL, acc[0][NS], 0, 0, 0); \
  acc[1][NS] = __builtin_amdgcn_mfma_f32_16x16x32_bf16(f.Ah1, f.BL, acc[1][NS], 0, 0, 0); \
  acc[0][NS] = __builtin_amdgcn_mfma_f32_16x16x32_bf16(f.Al0, f.BH, acc[0][NS], 0, 0, 0); \
  acc[1][NS] = __builtin_amdgcn_mfma_f32_16x16x32_bf16(f.Al1, f.BH, acc[1][NS], 0, 0, 0);
  MF1(0, Bh0, Bl0)
  MF1(1, Bh1, Bl1)
  MF1(2, Bh2, Bl2)
  MF1(3, Bh3, Bl3)
#undef MF1
}

constexpr int EXR = 545;   // epilogue LDS row stride (words); 545 % 32 = 1 -> no 4-way bank collision

__global__ __launch_bounds__(512) void sgp_mfma(
    const float* __restrict__ x,    // [B,F,8]
    const float* __restrict__ blft, // [1,F,1]
    const float* __restrict__ an,   // [F,4]
    const float* __restrict__ wgp,  // [F,20]
    const unsigned short* __restrict__ xh, const unsigned short* __restrict__ xl,
    const unsigned short* __restrict__ wh, const unsigned short* __restrict__ wlo,
    float* __restrict__ out)        // [B,F,8]
{
  constexpr Tables T = make_tables();

  __shared__ __align__(16) float ex[16 * EXR];   // 34880 B

  const int tid = threadIdx.x;
  const int wid = tid >> 6;              // wave id = blade id
  const int lane = tid & 63;

  // ---- XCD-aware bijective block swizzle (2048 blocks, 8 XCDs round-robin) ----
  const int lin = blockIdx.x;
  const int xcd = lin & 7;
  const int j = lin >> 3;                // per-XCD sequence 0..255
  const int bt = (xcd << 5) | (j >> 3);  // XCD owns 32 consecutive b-tiles
  const int nt = j & 7;                  // n-tile fastest within an XCD
  const int bb = bt << 5;
  const int nn = nt << 5;

  const int gI = T.gr[wid];
  const int l15 = lane & 15;
  const int klane = (lane >> 4) << 3;    // k-subchunk base for this lane (0,8,16,24)

  Ptrs P;
  P.aH0 = xh + ((size_t)wid << 21) + ((size_t)(bb + l15) << 8) + klane;
  P.aH1 = xh + ((size_t)wid << 21) + ((size_t)(bb + 16 + l15) << 8) + klane;
  P.aL0 = xl + ((size_t)wid << 21) + ((size_t)(bb + l15) << 8) + klane;
  P.aL1 = xl + ((size_t)wid << 21) + ((size_t)(bb + 16 + l15) << 8) + klane;
  {
    const int pl0 = gI;                  // left  plane
    const int pl1 = 4 + gI;              // right plane
    const int r0 = nn + l15, r1 = nn + 16 + l15;
    P.bH0 = wh  + ((size_t)pl0 << 16) + ((size_t)r0 << 8) + klane;
    P.bH1 = wh  + ((size_t)pl0 << 16) + ((size_t)r1 << 8) + klane;
    P.bH2 = wh  + ((size_t)pl1 << 16) + ((size_t)r0 << 8) + klane;
    P.bH3 = wh  + ((size_t)pl1 << 16) + ((size_t)r1 << 8) + klane;
    P.bL0 = wlo + ((size_t)pl0 << 16) + ((size_t)r0 << 8) + klane;
    P.bL1 = wlo + ((size_t)pl0 << 16) + ((size_t)r1 << 8) + klane;
    P.bL2 = wlo + ((size_t)pl1 << 16) + ((size_t)r0 << 8) + klane;
    P.bL3 = wlo + ((size_t)pl1 << 16) + ((size_t)r1 << 8) + klane;
  }

  f32x4 acc[2][4];
  #pragma unroll
  for (int a = 0; a < 2; ++a)
    #pragma unroll
    for (int c = 0; c < 4; ++c) acc[a][c] = (f32x4)(0.0f);

  // ---- K loop, fully unrolled, two register fragment sets in flight ----
  KF f0, f1;
  loadk(f0, P, 0);
  loadk(f1, P, 32);
  mfmak(f0, acc); loadk(f0, P, 64);
  mfmak(f1, acc); loadk(f1, P, 96);
  mfmak(f0, acc); loadk(f0, P, 128);
  mfmak(f1, acc); loadk(f1, P, 160);
  mfmak(f0, acc); loadk(f0, P, 192);
  mfmak(f1, acc); loadk(f1, P, 224);
  mfmak(f0, acc);
  mfmak(f1, acc);

  // ================= fused epilogue: exchange blades via LDS, norm + gp =========
  const float inv_sqrt2 = 0.7071067811865476f;

  #pragma unroll
  for (int c = 0; c < 2; ++c) {          // two 16-row b-chunks (== acc first index)
    if (c) __syncthreads();
    // D layout: col(n) = lane&15, row(m) = (lane>>4)*4 + reg
    #pragma unroll
    for (int ns = 0; ns < 4; ++ns) {
      const int n = ((ns & 1) << 4) + l15;
      const int so = ((ns >> 1) << 3) + wid;   // side*8 + blade
      #pragma unroll
      for (int r = 0; r < 4; ++r) {
        const int row = ((lane >> 4) << 2) + r;
        ex[row * EXR + n * 17 + so] = acc[c][ns][r];
      }
    }
    __syncthreads();

    // read + gp: one (b,n) pair per thread
    const int prow = tid >> 5, pn = tid & 31;
    const float* e = &ex[prow * EXR + pn * 17];
    float L[8], R[8];
    #pragma unroll
    for (int i = 0; i < 8; ++i) { L[i] = e[i]; R[i] = e[8 + i]; }

    const int b  = bb + (c << 4) + prow;
    const int ng = nn + pn;

    float4 anv = *(const float4*)(an + (size_t)ng * 4);
    const float bias = blft[ng];
    float wd[20];
    #pragma unroll
    for (int q = 0; q < 5; ++q) {
      float4 w4 = *(const float4*)(wgp + (size_t)ng * 20 + q * 4);
      wd[q * 4 + 0] = w4.x; wd[q * 4 + 1] = w4.y;
      wd[q * 4 + 2] = w4.z; wd[q * 4 + 3] = w4.w;
    }
    float sgm[4];
    sgm[0] = 1.f / (1.f + expf(-anv.x));
    sgm[1] = 1.f / (1.f + expf(-anv.y));
    sgm[2] = 1.f / (1.f + expf(-anv.z));
    sgm[3] = 1.f / (1.f + expf(-anv.w));

    float q0 = R[0] * R[0];
    float q1 = R[1] * R[1] + R[2] * R[2] + R[3] * R[3];
    float q2 = R[4] * R[4] + R[5] * R[5] + R[6] * R[6];
    float q3 = R[7] * R[7];
    float nrm[4];
    nrm[0] = sqrtf(sqrtf(q0 * q0 + 1e-16f));
    nrm[1] = sqrtf(sqrtf(q1 * q1 + 1e-16f));
    nrm[2] = sqrtf(sqrtf(q2 * q2 + 1e-16f));
    nrm[3] = sqrtf(sqrtf(q3 * q3 + 1e-16f));
    float invn[4];
    #pragma unroll
    for (int g = 0; g < 4; ++g)
      invn[g] = 1.0f / (sgm[g] * (nrm[g] - 1.0f) + 1.0f + 1e-6f);

    float xr[8];
    #pragma unroll
    for (int i = 0; i < 8; ++i) xr[i] = R[i] * invn[T.gr[i]];

    f8 xv = ld8(x + (((size_t)b << 8) + ng) * 8);

    float gp[8] = {0, 0, 0, 0, 0, 0, 0, 0};
    #pragma unroll
    for (int i = 0; i < 8; ++i) {
      #pragma unroll
      for (int k = 0; k < 8; ++k) {
        const int p = i * 8 + k;
        gp[T.jidx[p]] += T.sgn[p] * wd[T.path[p]] * xv.v[i] * xr[k];
      }
    }

    float o[8];
    #pragma unroll
    for (int i = 0; i < 8; ++i)
      o[i] = (L[i] + gp[i] + (i == 0 ? bias : 0.f)) * inv_sqrt2;

    float4* dst = (float4*)(out + (((size_t)b << 8) + ng) * 8);
    dst[0] = make_float4(o[0], o[1], o[2], o[3]);
    dst[1] = make_float4(o[4], o[5], o[6], o[7]);
  }
}

// ===================== legacy fallback (verified, 530us) ======================

constexpr int BT = 32;
constexpr int NT = 32;
constexpr int MT = 16;
constexpr int RS = 12;
constexpr int MS = BT * RS + 4;

__global__ __launch_bounds__(256) void sgp_fused(
    const float* __restrict__ x,
    const float* __restrict__ wl,
    const float* __restrict__ blft,
    const float* __restrict__ wr,
    const float* __restrict__ an,
    const float* __restrict__ wgp,
    float* __restrict__ out)
{
  constexpr Tables T = make_tables();

  __shared__ float xs[MT * MS];
  __shared__ float wsh[MT * MS];

  const int tid = threadIdx.x;
  const int tx = tid & 15;
  const int ty = tid >> 4;
  const int bb = blockIdx.x * BT;
  const int nn = blockIdx.y * NT;

  const int rl = tid >> 4;
  const int cm = tid & 15;

  float accL[2][2][8];
  float accR[2][2][8];
  #pragma unroll
  for (int a = 0; a < 2; ++a)
    #pragma unroll
    for (int c = 0; c < 2; ++c)
      #pragma unroll
      for (int i = 0; i < 8; ++i) { accL[a][c][i] = 0.f; accR[a][c][i] = 0.f; }

  for (int mm = 0; mm < Fsz; mm += MT) {
    {
      const float* g0 = x + (((size_t)(bb + rl)) * Fsz + (mm + cm)) * 8;
      const float* g1 = x + (((size_t)(bb + rl + 16)) * Fsz + (mm + cm)) * 8;
      float4 a0 = ((const float4*)g0)[0];
      float4 a1 = ((const float4*)g0)[1];
      float4 b0 = ((const float4*)g1)[0];
      float4 b1 = ((const float4*)g1)[1];
      *(float4*)&xs[cm * MS + rl * RS + 0] = a0;
      *(float4*)&xs[cm * MS + rl * RS + 4] = a1;
      *(float4*)&xs[cm * MS + (rl + 16) * RS + 0] = b0;
      *(float4*)&xs[cm * MS + (rl + 16) * RS + 4] = b1;
      float4 l0 = *(const float4*)(wl + (((size_t)(nn + rl)) * Fsz + (mm + cm)) * 4);
      float4 l1 = *(const float4*)(wl + (((size_t)(nn + rl + 16)) * Fsz + (mm + cm)) * 4);
      float4 r0 = *(const float4*)(wr + (((size_t)(nn + rl)) * Fsz + (mm + cm)) * 4);
      float4 r1 = *(const float4*)(wr + (((size_t)(nn + rl + 16)) * Fsz + (mm + cm)) * 4);
      *(float4*)&wsh[cm * MS + rl * RS + 0] = l0;
      *(float4*)&wsh[cm * MS + rl * RS + 4] = r0;
      *(float4*)&wsh[cm * MS + (rl + 16) * RS + 0] = l1;
      *(float4*)&wsh[cm * MS + (rl + 16) * RS + 4] = r1;
    }
    __syncthreads();

    #pragma unroll
    for (int m = 0; m < MT; ++m) {
      f8 xf0 = ld8(&xs[m * MS + ty * RS]);
      f8 xf1 = ld8(&xs[m * MS + (ty + 16) * RS]);
      f8 wv0 = ld8(&wsh[m * MS + tx * RS]);
      f8 wv1 = ld8(&wsh[m * MS + (tx + 16) * RS]);

      #pragma unroll
      for (int i = 0; i < 8; ++i) {
        const int g = T.gr[i];
        accL[0][0][i] += xf0.v[i] * wv0.v[g];
        accR[0][0][i] += xf0.v[i] * wv0.v[4 + g];
        accL[0][1][i] += xf0.v[i] * wv1.v[g];
        accR[0][1][i] += xf0.v[i] * wv1.v[4 + g];
        accL[1][0][i] += xf1.v[i] * wv0.v[g];
        accR[1][0][i] += xf1.v[i] * wv0.v[4 + g];
        accL[1][1][i] += xf1.v[i] * wv1.v[g];
        accR[1][1][i] += xf1.v[i] * wv1.v[4 + g];
      }
    }
    __syncthreads();
  }

  const float inv_sqrt2 = 0.7071067811865476f;

  #pragma unroll
  for (int c = 0; c < 2; ++c) {
    const int n = nn + tx + c * 16;
    float4 anv = *(const float4*)(an + (size_t)n * 4);
    const float bias = blft[n];
    float wd[20];
    #pragma unroll
    for (int q = 0; q < 5; ++q) {
      float4 w4 = *(const float4*)(wgp + (size_t)n * 20 + q * 4);
      wd[q * 4 + 0] = w4.x; wd[q * 4 + 1] = w4.y;
      wd[q * 4 + 2] = w4.z; wd[q * 4 + 3] = w4.w;
    }
    float sg[4];
    sg[0] = 1.f / (1.f + expf(-anv.x));
    sg[1] = 1.f / (1.f + expf(-anv.y));
    sg[2] = 1.f / (1.f + expf(-anv.z));
    sg[3] = 1.f / (1.f + expf(-anv.w));

    #pragma unroll
    for (int a = 0; a < 2; ++a) {
      const int b = bb + ty + a * 16;
      const float* r = accR[a][c];

      float q0 = r[0] * r[0];
      float q1 = r[1] * r[1] + r[2] * r[2] + r[3] * r[3];
      float q2 = r[4] * r[4] + r[5] * r[5] + r[6] * r[6];
      float q3 = r[7] * r[7];
      float nrm[4];
      nrm[0] = sqrtf(sqrtf(q0 * q0 + 1e-16f));
      nrm[1] = sqrtf(sqrtf(q1 * q1 + 1e-16f));
      nrm[2] = sqrtf(sqrtf(q2 * q2 + 1e-16f));
      nrm[3] = sqrtf(sqrtf(q3 * q3 + 1e-16f));
      float invn[4];
      #pragma unroll
      for (int g = 0; g < 4; ++g)
        invn[g] = 1.0f / (sg[g] * (nrm[g] - 1.0f) + 1.0f + 1e-6f);

      float xr[8];
      #pragma unroll
      for (int i = 0; i < 8; ++i) xr[i] = r[i] * invn[T.gr[i]];

      f8 xv = ld8(x + (((size_t)b) * Fsz + n) * 8);

      float gp[8] = {0, 0, 0, 0, 0, 0, 0, 0};
      #pragma unroll
      for (int i = 0; i < 8; ++i) {
        #pragma unroll
        for (int k = 0; k < 8; ++k) {
          const int p = i * 8 + k;
          gp[T.jidx[p]] += T.sgn[p] * wd[T.path[p]] * xv.v[i] * xr[k];
        }
      }

      float o[8];
      #pragma unroll
      for (int i = 0; i < 8; ++i)
        o[i] = (accL[a][c][i] + gp[i] + (i == 0 ? bias : 0.f)) * inv_sqrt2;

      float4* dst = (float4*)(out + (((size_t)b) * Fsz + n) * 8);
      dst[0] = make_float4(o[0], o[1], o[2], o[3]);
      dst[1] = make_float4(o[4], o[5], o[6], o[7]);
    }
  }
}

}  // namespace

extern "C" void kernel_launch(void* const* d_in, const int* in_sizes, int n_in,
                              void* d_out, int out_size, void* d_ws, size_t ws_size,
                              hipStream_t stream) {
  const float* x   = (const float*)d_in[0];
  const float* wl  = (const float*)d_in[1];
  const float* bl  = (const float*)d_in[2];
  const float* wr  = (const float*)d_in[3];
  const float* an  = (const float*)d_in[4];
  const float* wgp = (const float*)d_in[5];
  float* out = (float*)d_out;

  // workspace layout (ushort elements):
  //   xh [8][8192][256], xl same, wh [8][256][256], wlo same
  const size_t NXE = (size_t)8 * Bsz * Fsz;      // 16,777,216
  const size_t NWE = (size_t)8 * Fsz * Fsz;      //    524,288
  const size_t need = (2 * NXE + 2 * NWE) * sizeof(unsigned short);  // 69,206,016 B

  if (d_ws != nullptr && ws_size >= need) {
    unsigned short* xh  = (unsigned short*)d_ws;
    unsigned short* xl  = xh + NXE;
    unsigned short* wh  = xl + NXE;
    unsigned short* wlo = wh + NWE;

    prep_all<<<dim3(1536), dim3(256), 0, stream>>>(x, wl, wr, xh, xl, wh, wlo);
    sgp_mfma<<<dim3(2048), dim3(512), 0, stream>>>(
        x, bl, an, wgp, xh, xl, wh, wlo, out);
  } else {
    // fallback: verified fp32 VALU kernel
    dim3 grid(Bsz / BT, Fsz / NT);
    sgp_fused<<<grid, dim3(256), 0, stream>>>(x, wl, bl, wr, an, wgp, out);
  }
}

// Round 5
// 343.886 us; speedup vs baseline: 1.5429x; 1.0097x over previous
//
#include <hip/hip_runtime.h>
#include <math.h>

namespace {

constexpr int Bsz = 8192;
constexpr int Fsz = 256;

// ---------------- compile-time Clifford algebra tables (Cl(3,0)) ----------------
struct Tables {
  int   jidx[64];
  float sgn[64];
  int   path[64];
  int   gr[8];
};

constexpr int cpopc(int v) { int c = 0; while (v) { c += v & 1; v >>= 1; } return c; }

constexpr Tables make_tables() {
  Tables t{};
  constexpr int MASKS[8] = {0, 1, 2, 4, 3, 5, 6, 7};
  int inv[8] = {};
  for (int i = 0; i < 8; ++i) inv[MASKS[i]] = i;
  int grade[8] = {};
  for (int i = 0; i < 8; ++i) { grade[i] = cpopc(MASKS[i]); t.gr[i] = grade[i]; }
  int pidx[4][4][4] = {};
  for (int a = 0; a < 4; ++a)
    for (int b = 0; b < 4; ++b)
      for (int c = 0; c < 4; ++c) pidx[a][b][c] = -1;
  int np = 0;
  for (int gi = 0; gi < 4; ++gi)
    for (int gj = 0; gj < 4; ++gj)
      for (int gk = 0; gk < 4; ++gk) {
        bool any = false;
        for (int i = 0; i < 8; ++i)
          for (int k = 0; k < 8; ++k)
            if (grade[i] == gi && grade[k] == gk && cpopc(MASKS[i] ^ MASKS[k]) == gj) any = true;
        if (any) pidx[gi][gj][gk] = np++;
      }
  for (int i = 0; i < 8; ++i)
    for (int k = 0; k < 8; ++k) {
      const int mi = MASKS[i], mk = MASKS[k];
      int s = 0, aa = mi >> 1;
      while (aa) { s += cpopc(aa & mk); aa >>= 1; }
      t.jidx[i * 8 + k] = inv[mi ^ mk];
      t.sgn[i * 8 + k]  = (s & 1) ? -1.0f : 1.0f;
      t.path[i * 8 + k] = pidx[grade[i]][cpopc(mi ^ mk)][grade[k]];
    }
  return t;
}

typedef __attribute__((ext_vector_type(8))) short bf16x8;   // 8 bf16 = 4 VGPRs
typedef __attribute__((ext_vector_type(4))) float f32x4;    // MFMA accumulator

struct f8 { float v[8]; };

__device__ inline f8 ld8(const float* p) {
  f8 r;
  float4 a = *(const float4*)p;
  float4 b = *(const float4*)(p + 4);
  r.v[0] = a.x; r.v[1] = a.y; r.v[2] = a.z; r.v[3] = a.w;
  r.v[4] = b.x; r.v[5] = b.y; r.v[6] = b.z; r.v[7] = b.w;
  return r;
}

__device__ inline unsigned short f2bf(float f) {   // RNE fp32 -> bf16
  unsigned int u = __float_as_uint(f);
  unsigned int r = ((u >> 16) & 1u) + 0x7fffu;
  return (unsigned short)((u + r) >> 16);
}
__device__ inline float bf2f(unsigned short h) { return __uint_as_float(((unsigned int)h) << 16); }

// ===================== prep kernel: split fp32 into bf16 hi/lo =================
// (verified round-3 version, unchanged)
// blocks [0,1024): x [B,F,8] -> xh/xl [8][B][F]   (8 m-values per thread, 16B stores)
// blocks [1024,1536): wl/wr [F,F,4] -> wh/wlo [2*4][F(n)][F(m)]
__global__ __launch_bounds__(256) void prep_all(
    const float* __restrict__ x, const float* __restrict__ wl,
    const float* __restrict__ wr,
    unsigned short* __restrict__ xh, unsigned short* __restrict__ xl,
    unsigned short* __restrict__ wh, unsigned short* __restrict__ wlo)
{
  const int blk = blockIdx.x;
  if (blk < 1024) {
    const int t = blk * 256 + threadIdx.x;          // t < 262144
    const int b = t >> 5;
    const int m0 = (t & 31) << 3;                   // 8 consecutive m
    const float* src = x + (((size_t)b << 8) + m0) * 8;   // 64 floats
    float4 v[16];
    #pragma unroll
    for (int j = 0; j < 16; ++j) v[j] = ((const float4*)src)[j];
    const float* vf = (const float*)v;
    #pragma unroll
    for (int i = 0; i < 8; ++i) {
      unsigned int hw[4], lw[4];
      #pragma unroll
      for (int p = 0; p < 4; ++p) {
        float fa = vf[(2 * p) * 8 + i], fb = vf[(2 * p + 1) * 8 + i];
        unsigned short ha = f2bf(fa), hb = f2bf(fb);
        unsigned short la = f2bf(fa - bf2f(ha)), lb = f2bf(fb - bf2f(hb));
        hw[p] = (unsigned int)ha | ((unsigned int)hb << 16);
        lw[p] = (unsigned int)la | ((unsigned int)lb << 16);
      }
      const size_t o = ((size_t)i << 21) + ((size_t)b << 8) + m0;
      *(uint4*)(xh + o) = make_uint4(hw[0], hw[1], hw[2], hw[3]);
      *(uint4*)(xl + o) = make_uint4(lw[0], lw[1], lw[2], lw[3]);
    }
  } else {
    const int t = (blk - 1024) * 256 + threadIdx.x;  // t < 131072
    const int sg = t >> 14;                          // 0..7: s = sg>>2, g = sg&3
    const int s = sg >> 2, g = sg & 3;
    const int rem = t & 16383;
    const int n = rem >> 6;
    const int m0 = (rem & 63) << 2;
    const float* w = s ? wr : wl;
    ushort4 hv, lv;
    float f0 = w[(((size_t)n << 8) + m0 + 0) * 4 + g];
    float f1 = w[(((size_t)n << 8) + m0 + 1) * 4 + g];
    float f2 = w[(((size_t)n << 8) + m0 + 2) * 4 + g];
    float f3 = w[(((size_t)n << 8) + m0 + 3) * 4 + g];
    hv.x = f2bf(f0); hv.y = f2bf(f1); hv.z = f2bf(f2); hv.w = f2bf(f3);
    lv.x = f2bf(f0 - bf2f(hv.x)); lv.y = f2bf(f1 - bf2f(hv.y));
    lv.z = f2bf(f2 - bf2f(hv.z)); lv.w = f2bf(f3 - bf2f(hv.w));
    const size_t o = ((size_t)sg << 16) + ((size_t)n << 8) + m0;
    *(ushort4*)(wh + o) = hv;
    *(ushort4*)(wlo + o) = lv;
  }
}

// ============ MFMA kernel: LDS-free split-bf16 GEMM + fused epilogue ===========
// Verified round-3 structure (2048 blocks XCD-swizzled, 32b x 32n per wave,
// named-field KF, EXR=545 epilogue). ONLY change this round: the K-loop is a
// depth-2 rotating register pipeline (f0/f1/f2) pinned with sched_barrier(0)
// at cluster boundaries, so the compiler cannot sink prefetch loads to their
// uses (round-3 failure signature: VGPR=68 -> serialized latency).
struct KF {
  bf16x8 Ah0, Ah1, Al0, Al1;
  bf16x8 Bh0, Bh1, Bh2, Bh3;
  bf16x8 Bl0, Bl1, Bl2, Bl3;
};

struct Ptrs {
  const unsigned short *aH0, *aH1, *aL0, *aL1;
  const unsigned short *bH0, *bH1, *bH2, *bH3;
  const unsigned short *bL0, *bL1, *bL2, *bL3;
};

__device__ __forceinline__ void loadk(KF& f, const Ptrs& p, int ko) {
  f.Ah0 = *(const bf16x8*)(p.aH0 + ko); f.Ah1 = *(const bf16x8*)(p.aH1 + ko);
  f.Al0 = *(const bf16x8*)(p.aL0 + ko); f.Al1 = *(const bf16x8*)(p.aL1 + ko);
  f.Bh0 = *(const bf16x8*)(p.bH0 + ko); f.Bh1 = *(const bf16x8*)(p.bH1 + ko);
  f.Bh2 = *(const bf16x8*)(p.bH2 + ko); f.Bh3 = *(const bf16x8*)(p.bH3 + ko);
  f.Bl0 = *(const bf16x8*)(p.bL0 + ko); f.Bl1 = *(const bf16x8*)(p.bL1 + ko);
  f.Bl2 = *(const bf16x8*)(p.bL2 + ko); f.Bl3 = *(const bf16x8*)(p.bL3 + ko);
}

__device__ __forceinline__ void mfmak(const KF& f, f32x4 (&acc)[2][4]) {
#define MF1(NS, BH, BL) \
  acc[0][NS] = __builtin_amdgcn_mfma_f32_16x16x32_bf16(f.Ah0, f.BH, acc[0][NS], 0, 0, 0); \
  acc[1][NS] = __builtin_amdgcn_mfma_f32_16x16x32_bf16(f.Ah1, f.BH, acc[1][NS], 0, 0, 0); \
  acc[0][NS] = __builtin_amdgcn_mfma_f32_16x16x32_bf16(f.Ah0, f.BL, acc[0][NS], 0, 0, 0); \
  acc[1][NS] = __builtin_amdgcn_mfma_f32_16x16x32_bf16(f.Ah1, f.BL, acc[1][NS], 0, 0, 0); \
  acc[0][NS] = __builtin_amdgcn_mfma_f32_16x16x32_bf16(f.Al0, f.BH, acc[0][NS], 0, 0, 0); \
  acc[1][NS] = __builtin_amdgcn_mfma_f32_16x16x32_bf16(f.Al1, f.BH, acc[1][NS], 0, 0, 0);
  MF1(0, Bh0, Bl0)
  MF1(1, Bh1, Bl1)
  MF1(2, Bh2, Bl2)
  MF1(3, Bh3, Bl3)
#undef MF1
}

#define SB() __builtin_amdgcn_sched_barrier(0)

constexpr int EXR = 545;   // epilogue LDS row stride (words); 545 % 32 = 1

__global__ __launch_bounds__(512) void sgp_mfma(
    const float* __restrict__ x,    // [B,F,8]
    const float* __restrict__ blft, // [1,F,1]
    const float* __restrict__ an,   // [F,4]
    const float* __restrict__ wgp,  // [F,20]
    const unsigned short* __restrict__ xh, const unsigned short* __restrict__ xl,
    const unsigned short* __restrict__ wh, const unsigned short* __restrict__ wlo,
    float* __restrict__ out)        // [B,F,8]
{
  constexpr Tables T = make_tables();

  __shared__ __align__(16) float ex[16 * EXR];   // 34880 B

  const int tid = threadIdx.x;
  const int wid = tid >> 6;              // wave id = blade id
  const int lane = tid & 63;

  // ---- XCD-aware bijective block swizzle (2048 blocks, 8 XCDs round-robin) ----
  const int lin = blockIdx.x;
  const int xcd = lin & 7;
  const int j = lin >> 3;                // per-XCD sequence 0..255
  const int bt = (xcd << 5) | (j >> 3);  // XCD owns 32 consecutive b-tiles
  const int nt = j & 7;                  // n-tile fastest within an XCD
  const int bb = bt << 5;
  const int nn = nt << 5;

  const int gI = T.gr[wid];
  const int l15 = lane & 15;
  const int klane = (lane >> 4) << 3;    // k-subchunk base for this lane (0,8,16,24)

  Ptrs P;
  P.aH0 = xh + ((size_t)wid << 21) + ((size_t)(bb + l15) << 8) + klane;
  P.aH1 = xh + ((size_t)wid << 21) + ((size_t)(bb + 16 + l15) << 8) + klane;
  P.aL0 = xl + ((size_t)wid << 21) + ((size_t)(bb + l15) << 8) + klane;
  P.aL1 = xl + ((size_t)wid << 21) + ((size_t)(bb + 16 + l15) << 8) + klane;
  {
    const int pl0 = gI;                  // left  plane
    const int pl1 = 4 + gI;              // right plane
    const int r0 = nn + l15, r1 = nn + 16 + l15;
    P.bH0 = wh  + ((size_t)pl0 << 16) + ((size_t)r0 << 8) + klane;
    P.bH1 = wh  + ((size_t)pl0 << 16) + ((size_t)r1 << 8) + klane;
    P.bH2 = wh  + ((size_t)pl1 << 16) + ((size_t)r0 << 8) + klane;
    P.bH3 = wh  + ((size_t)pl1 << 16) + ((size_t)r1 << 8) + klane;
    P.bL0 = wlo + ((size_t)pl0 << 16) + ((size_t)r0 << 8) + klane;
    P.bL1 = wlo + ((size_t)pl0 << 16) + ((size_t)r1 << 8) + klane;
    P.bL2 = wlo + ((size_t)pl1 << 16) + ((size_t)r0 << 8) + klane;
    P.bL3 = wlo + ((size_t)pl1 << 16) + ((size_t)r1 << 8) + klane;
  }

  f32x4 acc[2][4];
  #pragma unroll
  for (int a = 0; a < 2; ++a)
    #pragma unroll
    for (int c = 0; c < 4; ++c) acc[a][c] = (f32x4)(0.0f);

  // ---- K loop: depth-2 rotating register pipeline, sched_barrier-pinned ----
  // Consumption order f0,f1,f2,f0,f1,f2,f0,f1; each loadk(X) refills X only
  // after mfmak consumed X's previous tile (WAR safe in program order).
  KF f0, f1, f2;
  loadk(f0, P, 0);    SB();
  loadk(f1, P, 32);   SB();
  loadk(f2, P, 64);   SB();
  mfmak(f0, acc);     SB();
  loadk(f0, P, 96);   SB();
  mfmak(f1, acc);     SB();
  loadk(f1, P, 128);  SB();
  mfmak(f2, acc);     SB();
  loadk(f2, P, 160);  SB();
  mfmak(f0, acc);     SB();
  loadk(f0, P, 192);  SB();
  mfmak(f1, acc);     SB();
  loadk(f1, P, 224);  SB();
  mfmak(f2, acc);     SB();
  mfmak(f0, acc);     SB();
  mfmak(f1, acc);

  // ================= fused epilogue: exchange blades via LDS, norm + gp =========
  const float inv_sqrt2 = 0.7071067811865476f;

  #pragma unroll
  for (int c = 0; c < 2; ++c) {          // two 16-row b-chunks (== acc first index)
    if (c) __syncthreads();
    // D layout: col(n) = lane&15, row(m) = (lane>>4)*4 + reg
    #pragma unroll
    for (int ns = 0; ns < 4; ++ns) {
      const int n = ((ns & 1) << 4) + l15;
      const int so = ((ns >> 1) << 3) + wid;   // side*8 + blade
      #pragma unroll
      for (int r = 0; r < 4; ++r) {
        const int row = ((lane >> 4) << 2) + r;
        ex[row * EXR + n * 17 + so] = acc[c][ns][r];
      }
    }
    __syncthreads();

    // read + gp: one (b,n) pair per thread
    const int prow = tid >> 5, pn = tid & 31;
    const float* e = &ex[prow * EXR + pn * 17];
    float L[8], R[8];
    #pragma unroll
    for (int i = 0; i < 8; ++i) { L[i] = e[i]; R[i] = e[8 + i]; }

    const int b  = bb + (c << 4) + prow;
    const int ng = nn + pn;

    float4 anv = *(const float4*)(an + (size_t)ng * 4);
    const float bias = blft[ng];
    float wd[20];
    #pragma unroll
    for (int q = 0; q < 5; ++q) {
      float4 w4 = *(const float4*)(wgp + (size_t)ng * 20 + q * 4);
      wd[q * 4 + 0] = w4.x; wd[q * 4 + 1] = w4.y;
      wd[q * 4 + 2] = w4.z; wd[q * 4 + 3] = w4.w;
    }
    float sgm[4];
    sgm[0] = 1.f / (1.f + expf(-anv.x));
    sgm[1] = 1.f / (1.f + expf(-anv.y));
    sgm[2] = 1.f / (1.f + expf(-anv.z));
    sgm[3] = 1.f / (1.f + expf(-anv.w));

    float q0 = R[0] * R[0];
    float q1 = R[1] * R[1] + R[2] * R[2] + R[3] * R[3];
    float q2 = R[4] * R[4] + R[5] * R[5] + R[6] * R[6];
    float q3 = R[7] * R[7];
    float nrm[4];
    nrm[0] = sqrtf(sqrtf(q0 * q0 + 1e-16f));
    nrm[1] = sqrtf(sqrtf(q1 * q1 + 1e-16f));
    nrm[2] = sqrtf(sqrtf(q2 * q2 + 1e-16f));
    nrm[3] = sqrtf(sqrtf(q3 * q3 + 1e-16f));
    float invn[4];
    #pragma unroll
    for (int g = 0; g < 4; ++g)
      invn[g] = 1.0f / (sgm[g] * (nrm[g] - 1.0f) + 1.0f + 1e-6f);

    float xr[8];
    #pragma unroll
    for (int i = 0; i < 8; ++i) xr[i] = R[i] * invn[T.gr[i]];

    f8 xv = ld8(x + (((size_t)b << 8) + ng) * 8);

    float gp[8] = {0, 0, 0, 0, 0, 0, 0, 0};
    #pragma unroll
    for (int i = 0; i < 8; ++i) {
      #pragma unroll
      for (int k = 0; k < 8; ++k) {
        const int p = i * 8 + k;
        gp[T.jidx[p]] += T.sgn[p] * wd[T.path[p]] * xv.v[i] * xr[k];
      }
    }

    float o[8];
    #pragma unroll
    for (int i = 0; i < 8; ++i)
      o[i] = (L[i] + gp[i] + (i == 0 ? bias : 0.f)) * inv_sqrt2;

    float4* dst = (float4*)(out + (((size_t)b << 8) + ng) * 8);
    dst[0] = make_float4(o[0], o[1], o[2], o[3]);
    dst[1] = make_float4(o[4], o[5], o[6], o[7]);
  }
}

// ===================== legacy fallback (verified, 530us) ======================

constexpr int BT = 32;
constexpr int NT = 32;
constexpr int MT = 16;
constexpr int RS = 12;
constexpr int MS = BT * RS + 4;

__global__ __launch_bounds__(256) void sgp_fused(
    const float* __restrict__ x,
    const float* __restrict__ wl,
    const float* __restrict__ blft,
    const float* __restrict__ wr,
    const float* __restrict__ an,
    const float* __restrict__ wgp,
    float* __restrict__ out)
{
  constexpr Tables T = make_tables();

  __shared__ float xs[MT * MS];
  __shared__ float wsh[MT * MS];

  const int tid = threadIdx.x;
  const int tx = tid & 15;
  const int ty = tid >> 4;
  const int bb = blockIdx.x * BT;
  const int nn = blockIdx.y * NT;

  const int rl = tid >> 4;
  const int cm = tid & 15;

  float accL[2][2][8];
  float accR[2][2][8];
  #pragma unroll
  for (int a = 0; a < 2; ++a)
    #pragma unroll
    for (int c = 0; c < 2; ++c)
      #pragma unroll
      for (int i = 0; i < 8; ++i) { accL[a][c][i] = 0.f; accR[a][c][i] = 0.f; }

  for (int mm = 0; mm < Fsz; mm += MT) {
    {
      const float* g0 = x + (((size_t)(bb + rl)) * Fsz + (mm + cm)) * 8;
      const float* g1 = x + (((size_t)(bb + rl + 16)) * Fsz + (mm + cm)) * 8;
      float4 a0 = ((const float4*)g0)[0];
      float4 a1 = ((const float4*)g0)[1];
      float4 b0 = ((const float4*)g1)[0];
      float4 b1 = ((const float4*)g1)[1];
      *(float4*)&xs[cm * MS + rl * RS + 0] = a0;
      *(float4*)&xs[cm * MS + rl * RS + 4] = a1;
      *(float4*)&xs[cm * MS + (rl + 16) * RS + 0] = b0;
      *(float4*)&xs[cm * MS + (rl + 16) * RS + 4] = b1;
      float4 l0 = *(const float4*)(wl + (((size_t)(nn + rl)) * Fsz + (mm + cm)) * 4);
      float4 l1 = *(const float4*)(wl + (((size_t)(nn + rl + 16)) * Fsz + (mm + cm)) * 4);
      float4 r0 = *(const float4*)(wr + (((size_t)(nn + rl)) * Fsz + (mm + cm)) * 4);
      float4 r1 = *(const float4*)(wr + (((size_t)(nn + rl + 16)) * Fsz + (mm + cm)) * 4);
      *(float4*)&wsh[cm * MS + rl * RS + 0] = l0;
      *(float4*)&wsh[cm * MS + rl * RS + 4] = r0;
      *(float4*)&wsh[cm * MS + (rl + 16) * RS + 0] = l1;
      *(float4*)&wsh[cm * MS + (rl + 16) * RS + 4] = r1;
    }
    __syncthreads();

    #pragma unroll
    for (int m = 0; m < MT; ++m) {
      f8 xf0 = ld8(&xs[m * MS + ty * RS]);
      f8 xf1 = ld8(&xs[m * MS + (ty + 16) * RS]);
      f8 wv0 = ld8(&wsh[m * MS + tx * RS]);
      f8 wv1 = ld8(&wsh[m * MS + (tx + 16) * RS]);

      #pragma unroll
      for (int i = 0; i < 8; ++i) {
        const int g = T.gr[i];
        accL[0][0][i] += xf0.v[i] * wv0.v[g];
        accR[0][0][i] += xf0.v[i] * wv0.v[4 + g];
        accL[0][1][i] += xf0.v[i] * wv1.v[g];
        accR[0][1][i] += xf0.v[i] * wv1.v[4 + g];
        accL[1][0][i] += xf1.v[i] * wv0.v[g];
        accR[1][0][i] += xf1.v[i] * wv0.v[4 + g];
        accL[1][1][i] += xf1.v[i] * wv1.v[g];
        accR[1][1][i] += xf1.v[i] * wv1.v[4 + g];
      }
    }
    __syncthreads();
  }

  const float inv_sqrt2 = 0.7071067811865476f;

  #pragma unroll
  for (int c = 0; c < 2; ++c) {
    const int n = nn + tx + c * 16;
    float4 anv = *(const float4*)(an + (size_t)n * 4);
    const float bias = blft[n];
    float wd[20];
    #pragma unroll
    for (int q = 0; q < 5; ++q) {
      float4 w4 = *(const float4*)(wgp + (size_t)n * 20 + q * 4);
      wd[q * 4 + 0] = w4.x; wd[q * 4 + 1] = w4.y;
      wd[q * 4 + 2] = w4.z; wd[q * 4 + 3] = w4.w;
    }
    float sg[4];
    sg[0] = 1.f / (1.f + expf(-anv.x));
    sg[1] = 1.f / (1.f + expf(-anv.y));
    sg[2] = 1.f / (1.f + expf(-anv.z));
    sg[3] = 1.f / (1.f + expf(-anv.w));

    #pragma unroll
    for (int a = 0; a < 2; ++a) {
      const int b = bb + ty + a * 16;
      const float* r = accR[a][c];

      float q0 = r[0] * r[0];
      float q1 = r[1] * r[1] + r[2] * r[2] + r[3] * r[3];
      float q2 = r[4] * r[4] + r[5] * r[5] + r[6] * r[6];
      float q3 = r[7] * r[7];
      float nrm[4];
      nrm[0] = sqrtf(sqrtf(q0 * q0 + 1e-16f));
      nrm[1] = sqrtf(sqrtf(q1 * q1 + 1e-16f));
      nrm[2] = sqrtf(sqrtf(q2 * q2 + 1e-16f));
      nrm[3] = sqrtf(sqrtf(q3 * q3 + 1e-16f));
      float invn[4];
      #pragma unroll
      for (int g = 0; g < 4; ++g)
        invn[g] = 1.0f / (sg[g] * (nrm[g] - 1.0f) + 1.0f + 1e-6f);

      float xr[8];
      #pragma unroll
      for (int i = 0; i < 8; ++i) xr[i] = r[i] * invn[T.gr[i]];

      f8 xv = ld8(x + (((size_t)b) * Fsz + n) * 8);

      float gp[8] = {0, 0, 0, 0, 0, 0, 0, 0};
      #pragma unroll
      for (int i = 0; i < 8; ++i) {
        #pragma unroll
        for (int k = 0; k < 8; ++k) {
          const int p = i * 8 + k;
          gp[T.jidx[p]] += T.sgn[p] * wd[T.path[p]] * xv.v[i] * xr[k];
        }
      }

      float o[8];
      #pragma unroll
      for (int i = 0; i < 8; ++i)
        o[i] = (accL[a][c][i] + gp[i] + (i == 0 ? bias : 0.f)) * inv_sqrt2;

      float4* dst = (float4*)(out + (((size_t)b) * Fsz + n) * 8);
      dst[0] = make_float4(o[0], o[1], o[2], o[3]);
      dst[1] = make_float4(o[4], o[5], o[6], o[7]);
    }
  }
}

}  // namespace

extern "C" void kernel_launch(void* const* d_in, const int* in_sizes, int n_in,
                              void* d_out, int out_size, void* d_ws, size_t ws_size,
                              hipStream_t stream) {
  const float* x   = (const float*)d_in[0];
  const float* wl  = (const float*)d_in[1];
  const float* bl  = (const float*)d_in[2];
  const float* wr  = (const float*)d_in[3];
  const float* an  = (const float*)d_in[4];
  const float* wgp = (const float*)d_in[5];
  float* out = (float*)d_out;

  // workspace layout (ushort elements):
  //   xh [8][8192][256], xl same, wh [8][256][256], wlo same
  const size_t NXE = (size_t)8 * Bsz * Fsz;      // 16,777,216
  const size_t NWE = (size_t)8 * Fsz * Fsz;      //    524,288
  const size_t need = (2 * NXE + 2 * NWE) * sizeof(unsigned short);  // 69,206,016 B

  if (d_ws != nullptr && ws_size >= need) {
    unsigned short* xh  = (unsigned short*)d_ws;
    unsigned short* xl  = xh + NXE;
    unsigned short* wh  = xl + NXE;
    unsigned short* wlo = wh + NWE;

    prep_all<<<dim3(1536), dim3(256), 0, stream>>>(x, wl, wr, xh, xl, wh, wlo);
    sgp_mfma<<<dim3(2048), dim3(512), 0, stream>>>(
        x, bl, an, wgp, xh, xl, wh, wlo, out);
  } else {
    // fallback: verified fp32 VALU kernel
    dim3 grid(Bsz / BT, Fsz / NT);
    sgp_fused<<<grid, dim3(256), 0, stream>>>(x, wl, bl, wr, an, wgp, out);
  }
}

// Round 8
// 246.641 us; speedup vs baseline: 2.1512x; 1.3943x over previous
//
#include <hip/hip_runtime.h>
#include <math.h>

namespace {

constexpr int Bsz = 8192;
constexpr int Fsz = 256;

// ---------------- compile-time Clifford algebra tables (Cl(3,0)) ----------------
struct Tables {
  int   jidx[64];
  float sgn[64];
  int   path[64];
  int   gr[8];
};

constexpr int cpopc(int v) { int c = 0; while (v) { c += v & 1; v >>= 1; } return c; }

constexpr Tables make_tables() {
  Tables t{};
  constexpr int MASKS[8] = {0, 1, 2, 4, 3, 5, 6, 7};
  int inv[8] = {};
  for (int i = 0; i < 8; ++i) inv[MASKS[i]] = i;
  int grade[8] = {};
  for (int i = 0; i < 8; ++i) { grade[i] = cpopc(MASKS[i]); t.gr[i] = grade[i]; }
  int pidx[4][4][4] = {};
  for (int a = 0; a < 4; ++a)
    for (int b = 0; b < 4; ++b)
      for (int c = 0; c < 4; ++c) pidx[a][b][c] = -1;
  int np = 0;
  for (int gi = 0; gi < 4; ++gi)
    for (int gj = 0; gj < 4; ++gj)
      for (int gk = 0; gk < 4; ++gk) {
        bool any = false;
        for (int i = 0; i < 8; ++i)
          for (int k = 0; k < 8; ++k)
            if (grade[i] == gi && grade[k] == gk && cpopc(MASKS[i] ^ MASKS[k]) == gj) any = true;
        if (any) pidx[gi][gj][gk] = np++;
      }
  for (int i = 0; i < 8; ++i)
    for (int k = 0; k < 8; ++k) {
      const int mi = MASKS[i], mk = MASKS[k];
      int s = 0, aa = mi >> 1;
      while (aa) { s += cpopc(aa & mk); aa >>= 1; }
      t.jidx[i * 8 + k] = inv[mi ^ mk];
      t.sgn[i * 8 + k]  = (s & 1) ? -1.0f : 1.0f;
      t.path[i * 8 + k] = pidx[grade[i]][cpopc(mi ^ mk)][grade[k]];
    }
  return t;
}

typedef __attribute__((ext_vector_type(8))) _Float16 f16x8;  // 8 f16 = 4 VGPRs
typedef __attribute__((ext_vector_type(4))) float f32x4;     // MFMA accumulator

struct f8 { float v[8]; };

__device__ inline f8 ld8(const float* p) {
  f8 r;
  float4 a = *(const float4*)p;
  float4 b = *(const float4*)(p + 4);
  r.v[0] = a.x; r.v[1] = a.y; r.v[2] = a.z; r.v[3] = a.w;
  r.v[4] = b.x; r.v[5] = b.y; r.v[6] = b.z; r.v[7] = b.w;
  return r;
}

__device__ __forceinline__ unsigned short f2h(float f) {  // fp32 -> f16 (RNE)
  _Float16 h = (_Float16)f;
  return __builtin_bit_cast(unsigned short, h);
}

// ===================== prep kernel: fp32 -> f16 planes =========================
// blocks [0,1024): x [B,F,8] -> xhf [8][B][F] f16  (8 m per thread, 16B stores)
// blocks [1024,1536): wl/wr [F,F,4] -> whf [2*4][F(n)][F(m)] f16
__global__ __launch_bounds__(256) void prep_all(
    const float* __restrict__ x, const float* __restrict__ wl,
    const float* __restrict__ wr,
    unsigned short* __restrict__ xhf, unsigned short* __restrict__ whf)
{
  const int blk = blockIdx.x;
  if (blk < 1024) {
    const int t = blk * 256 + threadIdx.x;          // t < 262144
    const int b = t >> 5;
    const int m0 = (t & 31) << 3;                   // 8 consecutive m
    const float* src = x + (((size_t)b << 8) + m0) * 8;   // 64 floats
    float4 v[16];
    #pragma unroll
    for (int j = 0; j < 16; ++j) v[j] = ((const float4*)src)[j];
    const float* vf = (const float*)v;
    #pragma unroll
    for (int i = 0; i < 8; ++i) {
      unsigned int w0 = (unsigned int)f2h(vf[0 * 8 + i]) | ((unsigned int)f2h(vf[1 * 8 + i]) << 16);
      unsigned int w1 = (unsigned int)f2h(vf[2 * 8 + i]) | ((unsigned int)f2h(vf[3 * 8 + i]) << 16);
      unsigned int w2 = (unsigned int)f2h(vf[4 * 8 + i]) | ((unsigned int)f2h(vf[5 * 8 + i]) << 16);
      unsigned int w3 = (unsigned int)f2h(vf[6 * 8 + i]) | ((unsigned int)f2h(vf[7 * 8 + i]) << 16);
      const size_t o = ((size_t)i << 21) + ((size_t)b << 8) + m0;
      *(uint4*)(xhf + o) = make_uint4(w0, w1, w2, w3);
    }
  } else {
    const int t = (blk - 1024) * 256 + threadIdx.x;  // t < 131072
    const int sg = t >> 14;                          // side*4 + grade
    const int s = sg >> 2, g = sg & 3;
    const int rem = t & 16383;
    const int n = rem >> 6;
    const int m0 = (rem & 63) << 2;
    const float* w = s ? wr : wl;
    ushort4 hv;
    hv.x = f2h(w[(((size_t)n << 8) + m0 + 0) * 4 + g]);
    hv.y = f2h(w[(((size_t)n << 8) + m0 + 1) * 4 + g]);
    hv.z = f2h(w[(((size_t)n << 8) + m0 + 2) * 4 + g]);
    hv.w = f2h(w[(((size_t)n << 8) + m0 + 3) * 4 + g]);
    const size_t o = ((size_t)sg << 16) + ((size_t)n << 8) + m0;
    *(ushort4*)(whf + o) = hv;
  }
}

// ====== MFMA kernel: f16 single-pass, LDS-FREE (round-5 verified skeleton) =====
// 2048 blocks XCD-swizzled, 512 threads = 8 waves, wave = blade, 32b x 32n tile.
// Fragments loaded DIRECTLY global->register (the shape that passed rounds 2/3/5).
// ONLY change vs round 5: split-bf16 3-pass -> f16 single-pass (6 loads + 8 MFMA
// per K-chunk instead of 12 + 24).
struct KF { f16x8 Ah0, Ah1, Bh0, Bh1, Bh2, Bh3; };

struct Ptrs {
  const unsigned short *aH0, *aH1;
  const unsigned short *bH0, *bH1, *bH2, *bH3;
};

__device__ __forceinline__ void loadk(KF& f, const Ptrs& p, int ko) {
  f.Ah0 = *(const f16x8*)(p.aH0 + ko); f.Ah1 = *(const f16x8*)(p.aH1 + ko);
  f.Bh0 = *(const f16x8*)(p.bH0 + ko); f.Bh1 = *(const f16x8*)(p.bH1 + ko);
  f.Bh2 = *(const f16x8*)(p.bH2 + ko); f.Bh3 = *(const f16x8*)(p.bH3 + ko);
}

__device__ __forceinline__ void mfmak(const KF& f, f32x4 (&acc)[2][4]) {
#define MF1(NS, BH) \
  acc[0][NS] = __builtin_amdgcn_mfma_f32_16x16x32_f16(f.Ah0, f.BH, acc[0][NS], 0, 0, 0); \
  acc[1][NS] = __builtin_amdgcn_mfma_f32_16x16x32_f16(f.Ah1, f.BH, acc[1][NS], 0, 0, 0);
  MF1(0, Bh0)
  MF1(1, Bh1)
  MF1(2, Bh2)
  MF1(3, Bh3)
#undef MF1
}

#define SB() __builtin_amdgcn_sched_barrier(0)

constexpr int EXR = 545;   // epilogue LDS row stride (words); 545 % 32 = 1

__global__ __launch_bounds__(512) void sgp_mfma(
    const float* __restrict__ x,    // [B,F,8]
    const float* __restrict__ blft, // [1,F,1]
    const float* __restrict__ an,   // [F,4]
    const float* __restrict__ wgp,  // [F,20]
    const unsigned short* __restrict__ xhf,  // [8][B][F] f16
    const unsigned short* __restrict__ whf,  // [8][F][F] f16
    float* __restrict__ out)        // [B,F,8]
{
  constexpr Tables T = make_tables();

  __shared__ __align__(16) float ex[16 * EXR];   // 34880 B (dedicated, as in r5)

  const int tid = threadIdx.x;
  const int wid = tid >> 6;              // wave id = blade id
  const int lane = tid & 63;

  // ---- XCD-aware bijective block swizzle (2048 blocks, 8 XCDs round-robin) ----
  const int lin = blockIdx.x;
  const int xcd = lin & 7;
  const int j = lin >> 3;                // per-XCD sequence 0..255
  const int bt = (xcd << 5) | (j >> 3);  // XCD owns 32 consecutive b-tiles
  const int nt = j & 7;                  // n-tile fastest within an XCD
  const int bb = bt << 5;
  const int nn = nt << 5;

  const int gI = T.gr[wid];
  const int l15 = lane & 15;
  const int klane = (lane >> 4) << 3;    // k-subchunk base for this lane (0,8,16,24)

  Ptrs P;
  P.aH0 = xhf + ((size_t)wid << 21) + ((size_t)(bb + l15) << 8) + klane;
  P.aH1 = xhf + ((size_t)wid << 21) + ((size_t)(bb + 16 + l15) << 8) + klane;
  {
    const int pl0 = gI;                  // left  plane
    const int pl1 = 4 + gI;              // right plane
    const int r0 = nn + l15, r1 = nn + 16 + l15;
    P.bH0 = whf + ((size_t)pl0 << 16) + ((size_t)r0 << 8) + klane;
    P.bH1 = whf + ((size_t)pl0 << 16) + ((size_t)r1 << 8) + klane;
    P.bH2 = whf + ((size_t)pl1 << 16) + ((size_t)r0 << 8) + klane;
    P.bH3 = whf + ((size_t)pl1 << 16) + ((size_t)r1 << 8) + klane;
  }

  f32x4 acc[2][4];
  #pragma unroll
  for (int a = 0; a < 2; ++a)
    #pragma unroll
    for (int c = 0; c < 4; ++c) acc[a][c] = (f32x4)(0.0f);

  // ---- K loop: rotating register pipeline (round-5 verified shape) ----
  KF f0, f1, f2;
  loadk(f0, P, 0);    SB();
  loadk(f1, P, 32);   SB();
  loadk(f2, P, 64);   SB();
  mfmak(f0, acc);     SB();
  loadk(f0, P, 96);   SB();
  mfmak(f1, acc);     SB();
  loadk(f1, P, 128);  SB();
  mfmak(f2, acc);     SB();
  loadk(f2, P, 160);  SB();
  mfmak(f0, acc);     SB();
  loadk(f0, P, 192);  SB();
  mfmak(f1, acc);     SB();
  loadk(f1, P, 224);  SB();
  mfmak(f2, acc);     SB();
  mfmak(f0, acc);     SB();
  mfmak(f1, acc);

  // ================= fused epilogue (verified): exchange via LDS, norm + gp =====
  const float inv_sqrt2 = 0.7071067811865476f;

  #pragma unroll
  for (int c = 0; c < 2; ++c) {          // two 16-row b-chunks (== acc first index)
    if (c) __syncthreads();
    // D layout: col(n) = lane&15, row(m) = (lane>>4)*4 + reg
    #pragma unroll
    for (int ns = 0; ns < 4; ++ns) {
      const int n = ((ns & 1) << 4) + l15;
      const int so = ((ns >> 1) << 3) + wid;   // side*8 + blade
      #pragma unroll
      for (int r = 0; r < 4; ++r) {
        const int row = ((lane >> 4) << 2) + r;
        ex[row * EXR + n * 17 + so] = acc[c][ns][r];
      }
    }
    __syncthreads();

    // read + gp: one (b,n) pair per thread
    const int prow = tid >> 5, pn = tid & 31;
    const float* e = &ex[prow * EXR + pn * 17];
    float L[8], R[8];
    #pragma unroll
    for (int i = 0; i < 8; ++i) { L[i] = e[i]; R[i] = e[8 + i]; }

    const int b  = bb + (c << 4) + prow;
    const int ng = nn + pn;

    float4 anv = *(const float4*)(an + (size_t)ng * 4);
    const float bias = blft[ng];
    float wd[20];
    #pragma unroll
    for (int q = 0; q < 5; ++q) {
      float4 w4 = *(const float4*)(wgp + (size_t)ng * 20 + q * 4);
      wd[q * 4 + 0] = w4.x; wd[q * 4 + 1] = w4.y;
      wd[q * 4 + 2] = w4.z; wd[q * 4 + 3] = w4.w;
    }
    float sgm[4];
    sgm[0] = 1.f / (1.f + expf(-anv.x));
    sgm[1] = 1.f / (1.f + expf(-anv.y));
    sgm[2] = 1.f / (1.f + expf(-anv.z));
    sgm[3] = 1.f / (1.f + expf(-anv.w));

    float q0 = R[0] * R[0];
    float q1 = R[1] * R[1] + R[2] * R[2] + R[3] * R[3];
    float q2 = R[4] * R[4] + R[5] * R[5] + R[6] * R[6];
    float q3 = R[7] * R[7];
    float nrm[4];
    nrm[0] = sqrtf(sqrtf(q0 * q0 + 1e-16f));
    nrm[1] = sqrtf(sqrtf(q1 * q1 + 1e-16f));
    nrm[2] = sqrtf(sqrtf(q2 * q2 + 1e-16f));
    nrm[3] = sqrtf(sqrtf(q3 * q3 + 1e-16f));
    float invn[4];
    #pragma unroll
    for (int g = 0; g < 4; ++g)
      invn[g] = 1.0f / (sgm[g] * (nrm[g] - 1.0f) + 1.0f + 1e-6f);

    float xr[8];
    #pragma unroll
    for (int i = 0; i < 8; ++i) xr[i] = R[i] * invn[T.gr[i]];

    f8 xv = ld8(x + (((size_t)b << 8) + ng) * 8);

    float gp[8] = {0, 0, 0, 0, 0, 0, 0, 0};
    #pragma unroll
    for (int i = 0; i < 8; ++i) {
      #pragma unroll
      for (int k = 0; k < 8; ++k) {
        const int p = i * 8 + k;
        gp[T.jidx[p]] += T.sgn[p] * wd[T.path[p]] * xv.v[i] * xr[k];
      }
    }

    float o[8];
    #pragma unroll
    for (int i = 0; i < 8; ++i)
      o[i] = (L[i] + gp[i] + (i == 0 ? bias : 0.f)) * inv_sqrt2;

    float4* dst = (float4*)(out + (((size_t)b << 8) + ng) * 8);
    dst[0] = make_float4(o[0], o[1], o[2], o[3]);
    dst[1] = make_float4(o[4], o[5], o[6], o[7]);
  }
}

// ===================== legacy fallback (verified, 530us) ======================

constexpr int BT = 32;
constexpr int NT = 32;
constexpr int MT = 16;
constexpr int RS = 12;
constexpr int MS = BT * RS + 4;

__global__ __launch_bounds__(256) void sgp_fused(
    const float* __restrict__ x,
    const float* __restrict__ wl,
    const float* __restrict__ blft,
    const float* __restrict__ wr,
    const float* __restrict__ an,
    const float* __restrict__ wgp,
    float* __restrict__ out)
{
  constexpr Tables T = make_tables();

  __shared__ float xs[MT * MS];
  __shared__ float wsh[MT * MS];

  const int tid = threadIdx.x;
  const int tx = tid & 15;
  const int ty = tid >> 4;
  const int bb = blockIdx.x * BT;
  const int nn = blockIdx.y * NT;

  const int rl = tid >> 4;
  const int cm = tid & 15;

  float accL[2][2][8];
  float accR[2][2][8];
  #pragma unroll
  for (int a = 0; a < 2; ++a)
    #pragma unroll
    for (int c = 0; c < 2; ++c)
      #pragma unroll
      for (int i = 0; i < 8; ++i) { accL[a][c][i] = 0.f; accR[a][c][i] = 0.f; }

  for (int mm = 0; mm < Fsz; mm += MT) {
    {
      const float* g0 = x + (((size_t)(bb + rl)) * Fsz + (mm + cm)) * 8;
      const float* g1 = x + (((size_t)(bb + rl + 16)) * Fsz + (mm + cm)) * 8;
      float4 a0 = ((const float4*)g0)[0];
      float4 a1 = ((const float4*)g0)[1];
      float4 b0 = ((const float4*)g1)[0];
      float4 b1 = ((const float4*)g1)[1];
      *(float4*)&xs[cm * MS + rl * RS + 0] = a0;
      *(float4*)&xs[cm * MS + rl * RS + 4] = a1;
      *(float4*)&xs[cm * MS + (rl + 16) * RS + 0] = b0;
      *(float4*)&xs[cm * MS + (rl + 16) * RS + 4] = b1;
      float4 l0 = *(const float4*)(wl + (((size_t)(nn + rl)) * Fsz + (mm + cm)) * 4);
      float4 l1 = *(const float4*)(wl + (((size_t)(nn + rl + 16)) * Fsz + (mm + cm)) * 4);
      float4 r0 = *(const float4*)(wr + (((size_t)(nn + rl)) * Fsz + (mm + cm)) * 4);
      float4 r1 = *(const float4*)(wr + (((size_t)(nn + rl + 16)) * Fsz + (mm + cm)) * 4);
      *(float4*)&wsh[cm * MS + rl * RS + 0] = l0;
      *(float4*)&wsh[cm * MS + rl * RS + 4] = r0;
      *(float4*)&wsh[cm * MS + (rl + 16) * RS + 0] = l1;
      *(float4*)&wsh[cm * MS + (rl + 16) * RS + 4] = r1;
    }
    __syncthreads();

    #pragma unroll
    for (int m = 0; m < MT; ++m) {
      f8 xf0 = ld8(&xs[m * MS + ty * RS]);
      f8 xf1 = ld8(&xs[m * MS + (ty + 16) * RS]);
      f8 wv0 = ld8(&wsh[m * MS + tx * RS]);
      f8 wv1 = ld8(&wsh[m * MS + (tx + 16) * RS]);

      #pragma unroll
      for (int i = 0; i < 8; ++i) {
        const int g = T.gr[i];
        accL[0][0][i] += xf0.v[i] * wv0.v[g];
        accR[0][0][i] += xf0.v[i] * wv0.v[4 + g];
        accL[0][1][i] += xf0.v[i] * wv1.v[g];
        accR[0][1][i] += xf0.v[i] * wv1.v[4 + g];
        accL[1][0][i] += xf1.v[i] * wv0.v[g];
        accR[1][0][i] += xf1.v[i] * wv0.v[4 + g];
        accL[1][1][i] += xf1.v[i] * wv1.v[g];
        accR[1][1][i] += xf1.v[i] * wv1.v[4 + g];
      }
    }
    __syncthreads();
  }

  const float inv_sqrt2 = 0.7071067811865476f;

  #pragma unroll
  for (int c = 0; c < 2; ++c) {
    const int n = nn + tx + c * 16;
    float4 anv = *(const float4*)(an + (size_t)n * 4);
    const float bias = blft[n];
    float wd[20];
    #pragma unroll
    for (int q = 0; q < 5; ++q) {
      float4 w4 = *(const float4*)(wgp + (size_t)n * 20 + q * 4);
      wd[q * 4 + 0] = w4.x; wd[q * 4 + 1] = w4.y;
      wd[q * 4 + 2] = w4.z; wd[q * 4 + 3] = w4.w;
    }
    float sg[4];
    sg[0] = 1.f / (1.f + expf(-anv.x));
    sg[1] = 1.f / (1.f + expf(-anv.y));
    sg[2] = 1.f / (1.f + expf(-anv.z));
    sg[3] = 1.f / (1.f + expf(-anv.w));

    #pragma unroll
    for (int a = 0; a < 2; ++a) {
      const int b = bb + ty + a * 16;
      const float* r = accR[a][c];

      float q0 = r[0] * r[0];
      float q1 = r[1] * r[1] + r[2] * r[2] + r[3] * r[3];
      float q2 = r[4] * r[4] + r[5] * r[5] + r[6] * r[6];
      float q3 = r[7] * r[7];
      float nrm[4];
      nrm[0] = sqrtf(sqrtf(q0 * q0 + 1e-16f));
      nrm[1] = sqrtf(sqrtf(q1 * q1 + 1e-16f));
      nrm[2] = sqrtf(sqrtf(q2 * q2 + 1e-16f));
      nrm[3] = sqrtf(sqrtf(q3 * q3 + 1e-16f));
      float invn[4];
      #pragma unroll
      for (int g = 0; g < 4; ++g)
        invn[g] = 1.0f / (sg[g] * (nrm[g] - 1.0f) + 1.0f + 1e-6f);

      float xr[8];
      #pragma unroll
      for (int i = 0; i < 8; ++i) xr[i] = r[i] * invn[T.gr[i]];

      f8 xv = ld8(x + (((size_t)b) * Fsz + n) * 8);

      float gp[8] = {0, 0, 0, 0, 0, 0, 0, 0};
      #pragma unroll
      for (int i = 0; i < 8; ++i) {
        #pragma unroll
        for (int k = 0; k < 8; ++k) {
          const int p = i * 8 + k;
          gp[T.jidx[p]] += T.sgn[p] * wd[T.path[p]] * xv.v[i] * xr[k];
        }
      }

      float o[8];
      #pragma unroll
      for (int i = 0; i < 8; ++i)
        o[i] = (accL[a][c][i] + gp[i] + (i == 0 ? bias : 0.f)) * inv_sqrt2;

      float4* dst = (float4*)(out + (((size_t)b) * Fsz + n) * 8);
      dst[0] = make_float4(o[0], o[1], o[2], o[3]);
      dst[1] = make_float4(o[4], o[5], o[6], o[7]);
    }
  }
}

}  // namespace

extern "C" void kernel_launch(void* const* d_in, const int* in_sizes, int n_in,
                              void* d_out, int out_size, void* d_ws, size_t ws_size,
                              hipStream_t stream) {
  const float* x   = (const float*)d_in[0];
  const float* wl  = (const float*)d_in[1];
  const float* bl  = (const float*)d_in[2];
  const float* wr  = (const float*)d_in[3];
  const float* an  = (const float*)d_in[4];
  const float* wgp = (const float*)d_in[5];
  float* out = (float*)d_out;

  // workspace layout (ushort elements): xhf [8][8192][256], whf [8][256][256]
  const size_t NXE = (size_t)8 * Bsz * Fsz;      // 16,777,216
  const size_t NWE = (size_t)8 * Fsz * Fsz;      //    524,288
  const size_t need = (NXE + NWE) * sizeof(unsigned short);  // 34,603,008 B

  if (d_ws != nullptr && ws_size >= need) {
    unsigned short* xhf = (unsigned short*)d_ws;
    unsigned short* whf = xhf + NXE;

    prep_all<<<dim3(1536), dim3(256), 0, stream>>>(x, wl, wr, xhf, whf);
    sgp_mfma<<<dim3(2048), dim3(512), 0, stream>>>(
        x, bl, an, wgp, xhf, whf, out);
  } else {
    // fallback: verified fp32 VALU kernel
    dim3 grid(Bsz / BT, Fsz / NT);
    sgp_fused<<<grid, dim3(256), 0, stream>>>(x, wl, bl, wr, an, wgp, out);
  }
}

// Round 9
// 219.631 us; speedup vs baseline: 2.4158x; 1.1230x over previous
//
#include <hip/hip_runtime.h>
#include <math.h>

namespace {

constexpr int Bsz = 8192;
constexpr int Fsz = 256;

// ---------------- compile-time Clifford algebra tables (Cl(3,0)) ----------------
struct Tables {
  int   jidx[64];
  float sgn[64];
  int   path[64];
  int   gr[8];
};

constexpr int cpopc(int v) { int c = 0; while (v) { c += v & 1; v >>= 1; } return c; }

constexpr Tables make_tables() {
  Tables t{};
  constexpr int MASKS[8] = {0, 1, 2, 4, 3, 5, 6, 7};
  int inv[8] = {};
  for (int i = 0; i < 8; ++i) inv[MASKS[i]] = i;
  int grade[8] = {};
  for (int i = 0; i < 8; ++i) { grade[i] = cpopc(MASKS[i]); t.gr[i] = grade[i]; }
  int pidx[4][4][4] = {};
  for (int a = 0; a < 4; ++a)
    for (int b = 0; b < 4; ++b)
      for (int c = 0; c < 4; ++c) pidx[a][b][c] = -1;
  int np = 0;
  for (int gi = 0; gi < 4; ++gi)
    for (int gj = 0; gj < 4; ++gj)
      for (int gk = 0; gk < 4; ++gk) {
        bool any = false;
        for (int i = 0; i < 8; ++i)
          for (int k = 0; k < 8; ++k)
            if (grade[i] == gi && grade[k] == gk && cpopc(MASKS[i] ^ MASKS[k]) == gj) any = true;
        if (any) pidx[gi][gj][gk] = np++;
      }
  for (int i = 0; i < 8; ++i)
    for (int k = 0; k < 8; ++k) {
      const int mi = MASKS[i], mk = MASKS[k];
      int s = 0, aa = mi >> 1;
      while (aa) { s += cpopc(aa & mk); aa >>= 1; }
      t.jidx[i * 8 + k] = inv[mi ^ mk];
      t.sgn[i * 8 + k]  = (s & 1) ? -1.0f : 1.0f;
      t.path[i * 8 + k] = pidx[grade[i]][cpopc(mi ^ mk)][grade[k]];
    }
  return t;
}

typedef __attribute__((ext_vector_type(8))) _Float16 f16x8;  // 8 f16 = 4 VGPRs
typedef __attribute__((ext_vector_type(4))) float f32x4;     // MFMA accumulator

struct f8 { float v[8]; };

__device__ inline f8 ld8(const float* p) {
  f8 r;
  float4 a = *(const float4*)p;
  float4 b = *(const float4*)(p + 4);
  r.v[0] = a.x; r.v[1] = a.y; r.v[2] = a.z; r.v[3] = a.w;
  r.v[4] = b.x; r.v[5] = b.y; r.v[6] = b.z; r.v[7] = b.w;
  return r;
}

__device__ __forceinline__ unsigned short f2h(float f) {  // fp32 -> f16 (RNE)
  _Float16 h = (_Float16)f;
  return __builtin_bit_cast(unsigned short, h);
}

// ===================== prep kernel: fp32 -> f16 planes (verified) ==============
// blocks [0,1024): x [B,F,8] -> xhf [8][B][F] f16  (8 m per thread, 16B stores)
// blocks [1024,1536): wl/wr [F,F,4] -> whf [2*4][F(n)][F(m)] f16
__global__ __launch_bounds__(256) void prep_all(
    const float* __restrict__ x, const float* __restrict__ wl,
    const float* __restrict__ wr,
    unsigned short* __restrict__ xhf, unsigned short* __restrict__ whf)
{
  const int blk = blockIdx.x;
  if (blk < 1024) {
    const int t = blk * 256 + threadIdx.x;          // t < 262144
    const int b = t >> 5;
    const int m0 = (t & 31) << 3;                   // 8 consecutive m
    const float* src = x + (((size_t)b << 8) + m0) * 8;   // 64 floats
    float4 v[16];
    #pragma unroll
    for (int j = 0; j < 16; ++j) v[j] = ((const float4*)src)[j];
    const float* vf = (const float*)v;
    #pragma unroll
    for (int i = 0; i < 8; ++i) {
      unsigned int w0 = (unsigned int)f2h(vf[0 * 8 + i]) | ((unsigned int)f2h(vf[1 * 8 + i]) << 16);
      unsigned int w1 = (unsigned int)f2h(vf[2 * 8 + i]) | ((unsigned int)f2h(vf[3 * 8 + i]) << 16);
      unsigned int w2 = (unsigned int)f2h(vf[4 * 8 + i]) | ((unsigned int)f2h(vf[5 * 8 + i]) << 16);
      unsigned int w3 = (unsigned int)f2h(vf[6 * 8 + i]) | ((unsigned int)f2h(vf[7 * 8 + i]) << 16);
      const size_t o = ((size_t)i << 21) + ((size_t)b << 8) + m0;
      *(uint4*)(xhf + o) = make_uint4(w0, w1, w2, w3);
    }
  } else {
    const int t = (blk - 1024) * 256 + threadIdx.x;  // t < 131072
    const int sg = t >> 14;                          // side*4 + grade
    const int s = sg >> 2, g = sg & 3;
    const int rem = t & 16383;
    const int n = rem >> 6;
    const int m0 = (rem & 63) << 2;
    const float* w = s ? wr : wl;
    ushort4 hv;
    hv.x = f2h(w[(((size_t)n << 8) + m0 + 0) * 4 + g]);
    hv.y = f2h(w[(((size_t)n << 8) + m0 + 1) * 4 + g]);
    hv.z = f2h(w[(((size_t)n << 8) + m0 + 2) * 4 + g]);
    hv.w = f2h(w[(((size_t)n << 8) + m0 + 3) * 4 + g]);
    const size_t o = ((size_t)sg << 16) + ((size_t)n << 8) + m0;
    *(ushort4*)(whf + o) = hv;
  }
}

// ====== MFMA kernel: f16 single-pass, LDS-free, NB=4 (64 b-rows per wave) ======
// 1024 blocks XCD-swizzled, 512 threads = 8 waves, wave = blade, 64b x 32n tile.
// ONLY change vs verified round 8: per-wave b-tile 32 -> 64 (NB=4): per K-chunk
// 8 loads feed 16 MFMAs (was 6:8), doubling busy-time per memory round-trip.
constexpr int NBR = 4;         // b-rowsets of 16 per wave

struct KF { f16x8 A[NBR]; f16x8 B[4]; };

struct Ptrs {
  const unsigned short* a[NBR];
  const unsigned short* b[4];
};

__device__ __forceinline__ void loadk(KF& f, const Ptrs& p, int ko) {
  #pragma unroll
  for (int r = 0; r < NBR; ++r) f.A[r] = *(const f16x8*)(p.a[r] + ko);
  #pragma unroll
  for (int n = 0; n < 4; ++n)  f.B[n] = *(const f16x8*)(p.b[n] + ko);
}

__device__ __forceinline__ void mfmak(const KF& f, f32x4 (&acc)[NBR][4]) {
  #pragma unroll
  for (int ns = 0; ns < 4; ++ns)
    #pragma unroll
    for (int r = 0; r < NBR; ++r)
      acc[r][ns] = __builtin_amdgcn_mfma_f32_16x16x32_f16(f.A[r], f.B[ns], acc[r][ns], 0, 0, 0);
}

#define SB() __builtin_amdgcn_sched_barrier(0)

constexpr int EXR = 545;   // epilogue LDS row stride (words); 545 % 32 = 1

__global__ __launch_bounds__(512) void sgp_mfma(
    const float* __restrict__ x,    // [B,F,8]
    const float* __restrict__ blft, // [1,F,1]
    const float* __restrict__ an,   // [F,4]
    const float* __restrict__ wgp,  // [F,20]
    const unsigned short* __restrict__ xhf,  // [8][B][F] f16
    const unsigned short* __restrict__ whf,  // [8][F][F] f16
    float* __restrict__ out)        // [B,F,8]
{
  constexpr Tables T = make_tables();

  __shared__ __align__(16) float ex[16 * EXR];   // 34880 B (dedicated)

  const int tid = threadIdx.x;
  const int wid = tid >> 6;              // wave id = blade id
  const int lane = tid & 63;

  // ---- XCD-aware bijective block swizzle (1024 blocks, 8 XCDs round-robin) ----
  const int lin = blockIdx.x;
  const int xcd = lin & 7;
  const int j = lin >> 3;                // 0..127
  const int bt = (xcd << 4) | (j >> 3);  // XCD owns 16 consecutive 64-row b-tiles
  const int nt = j & 7;                  // n-tile fastest within an XCD
  const int bb = bt << 6;                // 64 b-rows
  const int nn = nt << 5;                // 32 n-cols

  const int gI = T.gr[wid];
  const int l15 = lane & 15;
  const int klane = (lane >> 4) << 3;    // k-subchunk base for this lane (0,8,16,24)

  Ptrs P;
  #pragma unroll
  for (int r = 0; r < NBR; ++r)
    P.a[r] = xhf + ((size_t)wid << 21) + ((size_t)(bb + (r << 4) + l15) << 8) + klane;
  #pragma unroll
  for (int ns = 0; ns < 4; ++ns) {
    const int plane = ((ns >> 1) << 2) + gI;       // side*4 + grade
    P.b[ns] = whf + ((size_t)plane << 16)
            + ((size_t)(nn + ((ns & 1) << 4) + l15) << 8) + klane;
  }

  f32x4 acc[NBR][4];
  #pragma unroll
  for (int r = 0; r < NBR; ++r)
    #pragma unroll
    for (int c = 0; c < 4; ++c) acc[r][c] = (f32x4)(0.0f);

  // ---- K loop: rotating register pipeline (round-8 verified shape) ----
  KF f0, f1, f2;
  loadk(f0, P, 0);    SB();
  loadk(f1, P, 32);   SB();
  loadk(f2, P, 64);   SB();
  mfmak(f0, acc);     SB();
  loadk(f0, P, 96);   SB();
  mfmak(f1, acc);     SB();
  loadk(f1, P, 128);  SB();
  mfmak(f2, acc);     SB();
  loadk(f2, P, 160);  SB();
  mfmak(f0, acc);     SB();
  loadk(f0, P, 192);  SB();
  mfmak(f1, acc);     SB();
  loadk(f1, P, 224);  SB();
  mfmak(f2, acc);     SB();
  mfmak(f0, acc);     SB();
  mfmak(f1, acc);

  // ================= fused epilogue (verified): exchange via LDS, norm + gp =====
  const float inv_sqrt2 = 0.7071067811865476f;

  #pragma unroll
  for (int c = 0; c < NBR; ++c) {        // four 16-row b-chunks (== acc rowset)
    if (c) __syncthreads();
    // D layout: col(n) = lane&15, row(m) = (lane>>4)*4 + reg
    #pragma unroll
    for (int ns = 0; ns < 4; ++ns) {
      const int n = ((ns & 1) << 4) + l15;
      const int so = ((ns >> 1) << 3) + wid;   // side*8 + blade
      #pragma unroll
      for (int r = 0; r < 4; ++r) {
        const int row = ((lane >> 4) << 2) + r;
        ex[row * EXR + n * 17 + so] = acc[c][ns][r];
      }
    }
    __syncthreads();

    // read + gp: one (b,n) pair per thread
    const int prow = tid >> 5, pn = tid & 31;
    const float* e = &ex[prow * EXR + pn * 17];
    float L[8], R[8];
    #pragma unroll
    for (int i = 0; i < 8; ++i) { L[i] = e[i]; R[i] = e[8 + i]; }

    const int b  = bb + (c << 4) + prow;
    const int ng = nn + pn;

    float4 anv = *(const float4*)(an + (size_t)ng * 4);
    const float bias = blft[ng];
    float wd[20];
    #pragma unroll
    for (int q = 0; q < 5; ++q) {
      float4 w4 = *(const float4*)(wgp + (size_t)ng * 20 + q * 4);
      wd[q * 4 + 0] = w4.x; wd[q * 4 + 1] = w4.y;
      wd[q * 4 + 2] = w4.z; wd[q * 4 + 3] = w4.w;
    }
    float sgm[4];
    sgm[0] = 1.f / (1.f + expf(-anv.x));
    sgm[1] = 1.f / (1.f + expf(-anv.y));
    sgm[2] = 1.f / (1.f + expf(-anv.z));
    sgm[3] = 1.f / (1.f + expf(-anv.w));

    float q0 = R[0] * R[0];
    float q1 = R[1] * R[1] + R[2] * R[2] + R[3] * R[3];
    float q2 = R[4] * R[4] + R[5] * R[5] + R[6] * R[6];
    float q3 = R[7] * R[7];
    float nrm[4];
    nrm[0] = sqrtf(sqrtf(q0 * q0 + 1e-16f));
    nrm[1] = sqrtf(sqrtf(q1 * q1 + 1e-16f));
    nrm[2] = sqrtf(sqrtf(q2 * q2 + 1e-16f));
    nrm[3] = sqrtf(sqrtf(q3 * q3 + 1e-16f));
    float invn[4];
    #pragma unroll
    for (int g = 0; g < 4; ++g)
      invn[g] = 1.0f / (sgm[g] * (nrm[g] - 1.0f) + 1.0f + 1e-6f);

    float xr[8];
    #pragma unroll
    for (int i = 0; i < 8; ++i) xr[i] = R[i] * invn[T.gr[i]];

    f8 xv = ld8(x + (((size_t)b << 8) + ng) * 8);

    float gp[8] = {0, 0, 0, 0, 0, 0, 0, 0};
    #pragma unroll
    for (int i = 0; i < 8; ++i) {
      #pragma unroll
      for (int k = 0; k < 8; ++k) {
        const int p = i * 8 + k;
        gp[T.jidx[p]] += T.sgn[p] * wd[T.path[p]] * xv.v[i] * xr[k];
      }
    }

    float o[8];
    #pragma unroll
    for (int i = 0; i < 8; ++i)
      o[i] = (L[i] + gp[i] + (i == 0 ? bias : 0.f)) * inv_sqrt2;

    float4* dst = (float4*)(out + (((size_t)b << 8) + ng) * 8);
    dst[0] = make_float4(o[0], o[1], o[2], o[3]);
    dst[1] = make_float4(o[4], o[5], o[6], o[7]);
  }
}

// ===================== legacy fallback (verified, 530us) ======================

constexpr int BT = 32;
constexpr int NT = 32;
constexpr int MT = 16;
constexpr int RS = 12;
constexpr int MS = BT * RS + 4;

__global__ __launch_bounds__(256) void sgp_fused(
    const float* __restrict__ x,
    const float* __restrict__ wl,
    const float* __restrict__ blft,
    const float* __restrict__ wr,
    const float* __restrict__ an,
    const float* __restrict__ wgp,
    float* __restrict__ out)
{
  constexpr Tables T = make_tables();

  __shared__ float xs[MT * MS];
  __shared__ float wsh[MT * MS];

  const int tid = threadIdx.x;
  const int tx = tid & 15;
  const int ty = tid >> 4;
  const int bb = blockIdx.x * BT;
  const int nn = blockIdx.y * NT;

  const int rl = tid >> 4;
  const int cm = tid & 15;

  float accL[2][2][8];
  float accR[2][2][8];
  #pragma unroll
  for (int a = 0; a < 2; ++a)
    #pragma unroll
    for (int c = 0; c < 2; ++c)
      #pragma unroll
      for (int i = 0; i < 8; ++i) { accL[a][c][i] = 0.f; accR[a][c][i] = 0.f; }

  for (int mm = 0; mm < Fsz; mm += MT) {
    {
      const float* g0 = x + (((size_t)(bb + rl)) * Fsz + (mm + cm)) * 8;
      const float* g1 = x + (((size_t)(bb + rl + 16)) * Fsz + (mm + cm)) * 8;
      float4 a0 = ((const float4*)g0)[0];
      float4 a1 = ((const float4*)g0)[1];
      float4 b0 = ((const float4*)g1)[0];
      float4 b1 = ((const float4*)g1)[1];
      *(float4*)&xs[cm * MS + rl * RS + 0] = a0;
      *(float4*)&xs[cm * MS + rl * RS + 4] = a1;
      *(float4*)&xs[cm * MS + (rl + 16) * RS + 0] = b0;
      *(float4*)&xs[cm * MS + (rl + 16) * RS + 4] = b1;
      float4 l0 = *(const float4*)(wl + (((size_t)(nn + rl)) * Fsz + (mm + cm)) * 4);
      float4 l1 = *(const float4*)(wl + (((size_t)(nn + rl + 16)) * Fsz + (mm + cm)) * 4);
      float4 r0 = *(const float4*)(wr + (((size_t)(nn + rl)) * Fsz + (mm + cm)) * 4);
      float4 r1 = *(const float4*)(wr + (((size_t)(nn + rl + 16)) * Fsz + (mm + cm)) * 4);
      *(float4*)&wsh[cm * MS + rl * RS + 0] = l0;
      *(float4*)&wsh[cm * MS + rl * RS + 4] = r0;
      *(float4*)&wsh[cm * MS + (rl + 16) * RS + 0] = l1;
      *(float4*)&wsh[cm * MS + (rl + 16) * RS + 4] = r1;
    }
    __syncthreads();

    #pragma unroll
    for (int m = 0; m < MT; ++m) {
      f8 xf0 = ld8(&xs[m * MS + ty * RS]);
      f8 xf1 = ld8(&xs[m * MS + (ty + 16) * RS]);
      f8 wv0 = ld8(&wsh[m * MS + tx * RS]);
      f8 wv1 = ld8(&wsh[m * MS + (tx + 16) * RS]);

      #pragma unroll
      for (int i = 0; i < 8; ++i) {
        const int g = T.gr[i];
        accL[0][0][i] += xf0.v[i] * wv0.v[g];
        accR[0][0][i] += xf0.v[i] * wv0.v[4 + g];
        accL[0][1][i] += xf0.v[i] * wv1.v[g];
        accR[0][1][i] += xf0.v[i] * wv1.v[4 + g];
        accL[1][0][i] += xf1.v[i] * wv0.v[g];
        accR[1][0][i] += xf1.v[i] * wv0.v[4 + g];
        accL[1][1][i] += xf1.v[i] * wv1.v[g];
        accR[1][1][i] += xf1.v[i] * wv1.v[4 + g];
      }
    }
    __syncthreads();
  }

  const float inv_sqrt2 = 0.7071067811865476f;

  #pragma unroll
  for (int c = 0; c < 2; ++c) {
    const int n = nn + tx + c * 16;
    float4 anv = *(const float4*)(an + (size_t)n * 4);
    const float bias = blft[n];
    float wd[20];
    #pragma unroll
    for (int q = 0; q < 5; ++q) {
      float4 w4 = *(const float4*)(wgp + (size_t)n * 20 + q * 4);
      wd[q * 4 + 0] = w4.x; wd[q * 4 + 1] = w4.y;
      wd[q * 4 + 2] = w4.z; wd[q * 4 + 3] = w4.w;
    }
    float sg[4];
    sg[0] = 1.f / (1.f + expf(-anv.x));
    sg[1] = 1.f / (1.f + expf(-anv.y));
    sg[2] = 1.f / (1.f + expf(-anv.z));
    sg[3] = 1.f / (1.f + expf(-anv.w));

    #pragma unroll
    for (int a = 0; a < 2; ++a) {
      const int b = bb + ty + a * 16;
      const float* r = accR[a][c];

      float q0 = r[0] * r[0];
      float q1 = r[1] * r[1] + r[2] * r[2] + r[3] * r[3];
      float q2 = r[4] * r[4] + r[5] * r[5] + r[6] * r[6];
      float q3 = r[7] * r[7];
      float nrm[4];
      nrm[0] = sqrtf(sqrtf(q0 * q0 + 1e-16f));
      nrm[1] = sqrtf(sqrtf(q1 * q1 + 1e-16f));
      nrm[2] = sqrtf(sqrtf(q2 * q2 + 1e-16f));
      nrm[3] = sqrtf(sqrtf(q3 * q3 + 1e-16f));
      float invn[4];
      #pragma unroll
      for (int g = 0; g < 4; ++g)
        invn[g] = 1.0f / (sg[g] * (nrm[g] - 1.0f) + 1.0f + 1e-6f);

      float xr[8];
      #pragma unroll
      for (int i = 0; i < 8; ++i) xr[i] = r[i] * invn[T.gr[i]];

      f8 xv = ld8(x + (((size_t)b) * Fsz + n) * 8);

      float gp[8] = {0, 0, 0, 0, 0, 0, 0, 0};
      #pragma unroll
      for (int i = 0; i < 8; ++i) {
        #pragma unroll
        for (int k = 0; k < 8; ++k) {
          const int p = i * 8 + k;
          gp[T.jidx[p]] += T.sgn[p] * wd[T.path[p]] * xv.v[i] * xr[k];
        }
      }

      float o[8];
      #pragma unroll
      for (int i = 0; i < 8; ++i)
        o[i] = (accL[a][c][i] + gp[i] + (i == 0 ? bias : 0.f)) * inv_sqrt2;

      float4* dst = (float4*)(out + (((size_t)b) * Fsz + n) * 8);
      dst[0] = make_float4(o[0], o[1], o[2], o[3]);
      dst[1] = make_float4(o[4], o[5], o[6], o[7]);
    }
  }
}

}  // namespace

extern "C" void kernel_launch(void* const* d_in, const int* in_sizes, int n_in,
                              void* d_out, int out_size, void* d_ws, size_t ws_size,
                              hipStream_t stream) {
  const float* x   = (const float*)d_in[0];
  const float* wl  = (const float*)d_in[1];
  const float* bl  = (const float*)d_in[2];
  const float* wr  = (const float*)d_in[3];
  const float* an  = (const float*)d_in[4];
  const float* wgp = (const float*)d_in[5];
  float* out = (float*)d_out;

  // workspace layout (ushort elements): xhf [8][8192][256], whf [8][256][256]
  const size_t NXE = (size_t)8 * Bsz * Fsz;      // 16,777,216
  const size_t NWE = (size_t)8 * Fsz * Fsz;      //    524,288
  const size_t need = (NXE + NWE) * sizeof(unsigned short);  // 34,603,008 B

  if (d_ws != nullptr && ws_size >= need) {
    unsigned short* xhf = (unsigned short*)d_ws;
    unsigned short* whf = xhf + NXE;

    prep_all<<<dim3(1536), dim3(256), 0, stream>>>(x, wl, wr, xhf, whf);
    sgp_mfma<<<dim3(1024), dim3(512), 0, stream>>>(
        x, bl, an, wgp, xhf, whf, out);
  } else {
    // fallback: verified fp32 VALU kernel
    dim3 grid(Bsz / BT, Fsz / NT);
    sgp_fused<<<grid, dim3(256), 0, stream>>>(x, wl, bl, wr, an, wgp, out);
  }
}

// Round 10
// 211.699 us; speedup vs baseline: 2.5063x; 1.0375x over previous
//
#include <hip/hip_runtime.h>
#include <math.h>

namespace {

constexpr int Bsz = 8192;
constexpr int Fsz = 256;

// ---------------- compile-time Clifford algebra tables (Cl(3,0)) ----------------
struct Tables {
  int   jidx[64];
  float sgn[64];
  int   path[64];
  int   gr[8];
};

constexpr int cpopc(int v) { int c = 0; while (v) { c += v & 1; v >>= 1; } return c; }

constexpr Tables make_tables() {
  Tables t{};
  constexpr int MASKS[8] = {0, 1, 2, 4, 3, 5, 6, 7};
  int inv[8] = {};
  for (int i = 0; i < 8; ++i) inv[MASKS[i]] = i;
  int grade[8] = {};
  for (int i = 0; i < 8; ++i) { grade[i] = cpopc(MASKS[i]); t.gr[i] = grade[i]; }
  int pidx[4][4][4] = {};
  for (int a = 0; a < 4; ++a)
    for (int b = 0; b < 4; ++b)
      for (int c = 0; c < 4; ++c) pidx[a][b][c] = -1;
  int np = 0;
  for (int gi = 0; gi < 4; ++gi)
    for (int gj = 0; gj < 4; ++gj)
      for (int gk = 0; gk < 4; ++gk) {
        bool any = false;
        for (int i = 0; i < 8; ++i)
          for (int k = 0; k < 8; ++k)
            if (grade[i] == gi && grade[k] == gk && cpopc(MASKS[i] ^ MASKS[k]) == gj) any = true;
        if (any) pidx[gi][gj][gk] = np++;
      }
  for (int i = 0; i < 8; ++i)
    for (int k = 0; k < 8; ++k) {
      const int mi = MASKS[i], mk = MASKS[k];
      int s = 0, aa = mi >> 1;
      while (aa) { s += cpopc(aa & mk); aa >>= 1; }
      t.jidx[i * 8 + k] = inv[mi ^ mk];
      t.sgn[i * 8 + k]  = (s & 1) ? -1.0f : 1.0f;
      t.path[i * 8 + k] = pidx[grade[i]][cpopc(mi ^ mk)][grade[k]];
    }
  return t;
}

typedef __attribute__((ext_vector_type(8))) _Float16 f16x8;  // 8 f16 = 4 VGPRs
typedef __attribute__((ext_vector_type(4))) float f32x4;     // MFMA accumulator

struct f8 { float v[8]; };

__device__ inline f8 ld8(const float* p) {
  f8 r;
  float4 a = *(const float4*)p;
  float4 b = *(const float4*)(p + 4);
  r.v[0] = a.x; r.v[1] = a.y; r.v[2] = a.z; r.v[3] = a.w;
  r.v[4] = b.x; r.v[5] = b.y; r.v[6] = b.z; r.v[7] = b.w;
  return r;
}

__device__ __forceinline__ unsigned short f2h(float f) {  // fp32 -> f16 (RNE)
  _Float16 h = (_Float16)f;
  return __builtin_bit_cast(unsigned short, h);
}

// ===================== prep kernel: fp32 -> f16 planes =========================
// blocks [0,1024): x [B,F,8] -> xhf [8][B][F] via WAVE-PRIVATE LDS transpose.
//   Per wave per b-row: 8 fully-coalesced float4 loads (1KB/instr, lanes
//   contiguous -> full cache-line consumption, no L1 thrash), convert to packed
//   f16 pairs, write to private LDS [m][i-pair] (stride 5 u32), read back per
//   plane, emit fully-coalesced 16B plane stores. 2 rows per wave.
// blocks [1024,1536): wl/wr [F,F,4] -> whf [2*4][F(n)][F(m)] (unchanged).
__global__ __launch_bounds__(256) void prep_all(
    const float* __restrict__ x, const float* __restrict__ wl,
    const float* __restrict__ wr,
    unsigned short* __restrict__ xhf, unsigned short* __restrict__ whf)
{
  __shared__ __align__(16) unsigned int lt[4 * 1280];   // 4 waves x 5120 B
  const int blk = blockIdx.x;
  if (blk < 1024) {
    const int wv = threadIdx.x >> 6;
    const int l  = threadIdx.x & 63;
    unsigned int* L = lt + wv * 1280;

    for (int rr = 0; rr < 2; ++rr) {
      const int b = (blk << 3) + (wv << 1) + rr;
      const float* src = x + ((size_t)b << 11);          // b*256*8 floats
      // coalesced row read: lane l, chunk j -> float offset j*256 + 4l
      float4 v[8];
      #pragma unroll
      for (int j = 0; j < 8; ++j) v[j] = ((const float4*)src)[j * 64 + l];

      if (rr) __syncthreads();           // WAR: prev iteration's reads done
      // convert + transpose-write: float4 = (m = j*32 + l/2, i = 4(l&1)..+3)
      #pragma unroll
      for (int j = 0; j < 8; ++j) {
        const int m = (j << 5) + (l >> 1);
        const int c = (l & 1) << 1;      // i-pair index base (0 or 2)
        unsigned int u0 = (unsigned int)f2h(v[j].x) | ((unsigned int)f2h(v[j].y) << 16);
        unsigned int u1 = (unsigned int)f2h(v[j].z) | ((unsigned int)f2h(v[j].w) << 16);
        L[m * 5 + c]     = u0;
        L[m * 5 + c + 1] = u1;
      }
      __syncthreads();                   // write -> read ordering

      // read per-plane, assemble [f16(m)|f16(m+1)] words, coalesced 16B stores
      const int h  = l >> 5;             // plane parity handled by this half-wave
      const int mb = (l & 31) << 3;      // 8 consecutive m per lane
      #pragma unroll
      for (int s = 0; s < 4; ++s) {
        const int p  = (s << 1) + h;     // plane 0..7
        const int cw = p >> 1;           // i-pair word
        unsigned int o[4];
        #pragma unroll
        for (int r = 0; r < 4; ++r) {
          unsigned int A = L[(mb + 2 * r) * 5 + cw];
          unsigned int B = L[(mb + 2 * r + 1) * 5 + cw];
          o[r] = h ? ((A >> 16) | (B & 0xffff0000u))
                   : ((A & 0xffffu) | (B << 16));
        }
        const size_t d = ((size_t)p << 21) + ((size_t)b << 8) + mb;
        *(uint4*)(xhf + d) = make_uint4(o[0], o[1], o[2], o[3]);
      }
    }
  } else {
    const int t = (blk - 1024) * 256 + threadIdx.x;  // t < 131072
    const int sg = t >> 14;                          // side*4 + grade
    const int s = sg >> 2, g = sg & 3;
    const int rem = t & 16383;
    const int n = rem >> 6;
    const int m0 = (rem & 63) << 2;
    const float* w = s ? wr : wl;
    ushort4 hv;
    hv.x = f2h(w[(((size_t)n << 8) + m0 + 0) * 4 + g]);
    hv.y = f2h(w[(((size_t)n << 8) + m0 + 1) * 4 + g]);
    hv.z = f2h(w[(((size_t)n << 8) + m0 + 2) * 4 + g]);
    hv.w = f2h(w[(((size_t)n << 8) + m0 + 3) * 4 + g]);
    const size_t o = ((size_t)sg << 16) + ((size_t)n << 8) + m0;
    *(ushort4*)(whf + o) = hv;
  }
}

// ====== MFMA kernel: f16 single-pass, LDS-free, NB=4 (BYTE-IDENTICAL to r9) ====
constexpr int NBR = 4;         // b-rowsets of 16 per wave

struct KF { f16x8 A[NBR]; f16x8 B[4]; };

struct Ptrs {
  const unsigned short* a[NBR];
  const unsigned short* b[4];
};

__device__ __forceinline__ void loadk(KF& f, const Ptrs& p, int ko) {
  #pragma unroll
  for (int r = 0; r < NBR; ++r) f.A[r] = *(const f16x8*)(p.a[r] + ko);
  #pragma unroll
  for (int n = 0; n < 4; ++n)  f.B[n] = *(const f16x8*)(p.b[n] + ko);
}

__device__ __forceinline__ void mfmak(const KF& f, f32x4 (&acc)[NBR][4]) {
  #pragma unroll
  for (int ns = 0; ns < 4; ++ns)
    #pragma unroll
    for (int r = 0; r < NBR; ++r)
      acc[r][ns] = __builtin_amdgcn_mfma_f32_16x16x32_f16(f.A[r], f.B[ns], acc[r][ns], 0, 0, 0);
}

#define SB() __builtin_amdgcn_sched_barrier(0)

constexpr int EXR = 545;   // epilogue LDS row stride (words); 545 % 32 = 1

__global__ __launch_bounds__(512) void sgp_mfma(
    const float* __restrict__ x,    // [B,F,8]
    const float* __restrict__ blft, // [1,F,1]
    const float* __restrict__ an,   // [F,4]
    const float* __restrict__ wgp,  // [F,20]
    const unsigned short* __restrict__ xhf,  // [8][B][F] f16
    const unsigned short* __restrict__ whf,  // [8][F][F] f16
    float* __restrict__ out)        // [B,F,8]
{
  constexpr Tables T = make_tables();

  __shared__ __align__(16) float ex[16 * EXR];   // 34880 B (dedicated)

  const int tid = threadIdx.x;
  const int wid = tid >> 6;              // wave id = blade id
  const int lane = tid & 63;

  // ---- XCD-aware bijective block swizzle (1024 blocks, 8 XCDs round-robin) ----
  const int lin = blockIdx.x;
  const int xcd = lin & 7;
  const int j = lin >> 3;                // 0..127
  const int bt = (xcd << 4) | (j >> 3);  // XCD owns 16 consecutive 64-row b-tiles
  const int nt = j & 7;                  // n-tile fastest within an XCD
  const int bb = bt << 6;                // 64 b-rows
  const int nn = nt << 5;                // 32 n-cols

  const int gI = T.gr[wid];
  const int l15 = lane & 15;
  const int klane = (lane >> 4) << 3;    // k-subchunk base for this lane (0,8,16,24)

  Ptrs P;
  #pragma unroll
  for (int r = 0; r < NBR; ++r)
    P.a[r] = xhf + ((size_t)wid << 21) + ((size_t)(bb + (r << 4) + l15) << 8) + klane;
  #pragma unroll
  for (int ns = 0; ns < 4; ++ns) {
    const int plane = ((ns >> 1) << 2) + gI;       // side*4 + grade
    P.b[ns] = whf + ((size_t)plane << 16)
            + ((size_t)(nn + ((ns & 1) << 4) + l15) << 8) + klane;
  }

  f32x4 acc[NBR][4];
  #pragma unroll
  for (int r = 0; r < NBR; ++r)
    #pragma unroll
    for (int c = 0; c < 4; ++c) acc[r][c] = (f32x4)(0.0f);

  // ---- K loop: rotating register pipeline (round-9 verified shape) ----
  KF f0, f1, f2;
  loadk(f0, P, 0);    SB();
  loadk(f1, P, 32);   SB();
  loadk(f2, P, 64);   SB();
  mfmak(f0, acc);     SB();
  loadk(f0, P, 96);   SB();
  mfmak(f1, acc);     SB();
  loadk(f1, P, 128);  SB();
  mfmak(f2, acc);     SB();
  loadk(f2, P, 160);  SB();
  mfmak(f0, acc);     SB();
  loadk(f0, P, 192);  SB();
  mfmak(f1, acc);     SB();
  loadk(f1, P, 224);  SB();
  mfmak(f2, acc);     SB();
  mfmak(f0, acc);     SB();
  mfmak(f1, acc);

  // ================= fused epilogue (verified): exchange via LDS, norm + gp =====
  const float inv_sqrt2 = 0.7071067811865476f;

  #pragma unroll
  for (int c = 0; c < NBR; ++c) {        // four 16-row b-chunks (== acc rowset)
    if (c) __syncthreads();
    // D layout: col(n) = lane&15, row(m) = (lane>>4)*4 + reg
    #pragma unroll
    for (int ns = 0; ns < 4; ++ns) {
      const int n = ((ns & 1) << 4) + l15;
      const int so = ((ns >> 1) << 3) + wid;   // side*8 + blade
      #pragma unroll
      for (int r = 0; r < 4; ++r) {
        const int row = ((lane >> 4) << 2) + r;
        ex[row * EXR + n * 17 + so] = acc[c][ns][r];
      }
    }
    __syncthreads();

    // read + gp: one (b,n) pair per thread
    const int prow = tid >> 5, pn = tid & 31;
    const float* e = &ex[prow * EXR + pn * 17];
    float L[8], R[8];
    #pragma unroll
    for (int i = 0; i < 8; ++i) { L[i] = e[i]; R[i] = e[8 + i]; }

    const int b  = bb + (c << 4) + prow;
    const int ng = nn + pn;

    float4 anv = *(const float4*)(an + (size_t)ng * 4);
    const float bias = blft[ng];
    float wd[20];
    #pragma unroll
    for (int q = 0; q < 5; ++q) {
      float4 w4 = *(const float4*)(wgp + (size_t)ng * 20 + q * 4);
      wd[q * 4 + 0] = w4.x; wd[q * 4 + 1] = w4.y;
      wd[q * 4 + 2] = w4.z; wd[q * 4 + 3] = w4.w;
    }
    float sgm[4];
    sgm[0] = 1.f / (1.f + expf(-anv.x));
    sgm[1] = 1.f / (1.f + expf(-anv.y));
    sgm[2] = 1.f / (1.f + expf(-anv.z));
    sgm[3] = 1.f / (1.f + expf(-anv.w));

    float q0 = R[0] * R[0];
    float q1 = R[1] * R[1] + R[2] * R[2] + R[3] * R[3];
    float q2 = R[4] * R[4] + R[5] * R[5] + R[6] * R[6];
    float q3 = R[7] * R[7];
    float nrm[4];
    nrm[0] = sqrtf(sqrtf(q0 * q0 + 1e-16f));
    nrm[1] = sqrtf(sqrtf(q1 * q1 + 1e-16f));
    nrm[2] = sqrtf(sqrtf(q2 * q2 + 1e-16f));
    nrm[3] = sqrtf(sqrtf(q3 * q3 + 1e-16f));
    float invn[4];
    #pragma unroll
    for (int g = 0; g < 4; ++g)
      invn[g] = 1.0f / (sgm[g] * (nrm[g] - 1.0f) + 1.0f + 1e-6f);

    float xr[8];
    #pragma unroll
    for (int i = 0; i < 8; ++i) xr[i] = R[i] * invn[T.gr[i]];

    f8 xv = ld8(x + (((size_t)b << 8) + ng) * 8);

    float gp[8] = {0, 0, 0, 0, 0, 0, 0, 0};
    #pragma unroll
    for (int i = 0; i < 8; ++i) {
      #pragma unroll
      for (int k = 0; k < 8; ++k) {
        const int p = i * 8 + k;
        gp[T.jidx[p]] += T.sgn[p] * wd[T.path[p]] * xv.v[i] * xr[k];
      }
    }

    float o[8];
    #pragma unroll
    for (int i = 0; i < 8; ++i)
      o[i] = (L[i] + gp[i] + (i == 0 ? bias : 0.f)) * inv_sqrt2;

    float4* dst = (float4*)(out + (((size_t)b << 8) + ng) * 8);
    dst[0] = make_float4(o[0], o[1], o[2], o[3]);
    dst[1] = make_float4(o[4], o[5], o[6], o[7]);
  }
}

// ===================== legacy fallback (verified, 530us) ======================

constexpr int BT = 32;
constexpr int NT = 32;
constexpr int MT = 16;
constexpr int RS = 12;
constexpr int MS = BT * RS + 4;

__global__ __launch_bounds__(256) void sgp_fused(
    const float* __restrict__ x,
    const float* __restrict__ wl,
    const float* __restrict__ blft,
    const float* __restrict__ wr,
    const float* __restrict__ an,
    const float* __restrict__ wgp,
    float* __restrict__ out)
{
  constexpr Tables T = make_tables();

  __shared__ float xs[MT * MS];
  __shared__ float wsh[MT * MS];

  const int tid = threadIdx.x;
  const int tx = tid & 15;
  const int ty = tid >> 4;
  const int bb = blockIdx.x * BT;
  const int nn = blockIdx.y * NT;

  const int rl = tid >> 4;
  const int cm = tid & 15;

  float accL[2][2][8];
  float accR[2][2][8];
  #pragma unroll
  for (int a = 0; a < 2; ++a)
    #pragma unroll
    for (int c = 0; c < 2; ++c)
      #pragma unroll
      for (int i = 0; i < 8; ++i) { accL[a][c][i] = 0.f; accR[a][c][i] = 0.f; }

  for (int mm = 0; mm < Fsz; mm += MT) {
    {
      const float* g0 = x + (((size_t)(bb + rl)) * Fsz + (mm + cm)) * 8;
      const float* g1 = x + (((size_t)(bb + rl + 16)) * Fsz + (mm + cm)) * 8;
      float4 a0 = ((const float4*)g0)[0];
      float4 a1 = ((const float4*)g0)[1];
      float4 b0 = ((const float4*)g1)[0];
      float4 b1 = ((const float4*)g1)[1];
      *(float4*)&xs[cm * MS + rl * RS + 0] = a0;
      *(float4*)&xs[cm * MS + rl * RS + 4] = a1;
      *(float4*)&xs[cm * MS + (rl + 16) * RS + 0] = b0;
      *(float4*)&xs[cm * MS + (rl + 16) * RS + 4] = b1;
      float4 l0 = *(const float4*)(wl + (((size_t)(nn + rl)) * Fsz + (mm + cm)) * 4);
      float4 l1 = *(const float4*)(wl + (((size_t)(nn + rl + 16)) * Fsz + (mm + cm)) * 4);
      float4 r0 = *(const float4*)(wr + (((size_t)(nn + rl)) * Fsz + (mm + cm)) * 4);
      float4 r1 = *(const float4*)(wr + (((size_t)(nn + rl + 16)) * Fsz + (mm + cm)) * 4);
      *(float4*)&wsh[cm * MS + rl * RS + 0] = l0;
      *(float4*)&wsh[cm * MS + rl * RS + 4] = r0;
      *(float4*)&wsh[cm * MS + (rl + 16) * RS + 0] = l1;
      *(float4*)&wsh[cm * MS + (rl + 16) * RS + 4] = r1;
    }
    __syncthreads();

    #pragma unroll
    for (int m = 0; m < MT; ++m) {
      f8 xf0 = ld8(&xs[m * MS + ty * RS]);
      f8 xf1 = ld8(&xs[m * MS + (ty + 16) * RS]);
      f8 wv0 = ld8(&wsh[m * MS + tx * RS]);
      f8 wv1 = ld8(&wsh[m * MS + (tx + 16) * RS]);

      #pragma unroll
      for (int i = 0; i < 8; ++i) {
        const int g = T.gr[i];
        accL[0][0][i] += xf0.v[i] * wv0.v[g];
        accR[0][0][i] += xf0.v[i] * wv0.v[4 + g];
        accL[0][1][i] += xf0.v[i] * wv1.v[g];
        accR[0][1][i] += xf0.v[i] * wv1.v[4 + g];
        accL[1][0][i] += xf1.v[i] * wv0.v[g];
        accR[1][0][i] += xf1.v[i] * wv0.v[4 + g];
        accL[1][1][i] += xf1.v[i] * wv1.v[g];
        accR[1][1][i] += xf1.v[i] * wv1.v[4 + g];
      }
    }
    __syncthreads();
  }

  const float inv_sqrt2 = 0.7071067811865476f;

  #pragma unroll
  for (int c = 0; c < 2; ++c) {
    const int n = nn + tx + c * 16;
    float4 anv = *(const float4*)(an + (size_t)n * 4);
    const float bias = blft[n];
    float wd[20];
    #pragma unroll
    for (int q = 0; q < 5; ++q) {
      float4 w4 = *(const float4*)(wgp + (size_t)n * 20 + q * 4);
      wd[q * 4 + 0] = w4.x; wd[q * 4 + 1] = w4.y;
      wd[q * 4 + 2] = w4.z; wd[q * 4 + 3] = w4.w;
    }
    float sg[4];
    sg[0] = 1.f / (1.f + expf(-anv.x));
    sg[1] = 1.f / (1.f + expf(-anv.y));
    sg[2] = 1.f / (1.f + expf(-anv.z));
    sg[3] = 1.f / (1.f + expf(-anv.w));

    #pragma unroll
    for (int a = 0; a < 2; ++a) {
      const int b = bb + ty + a * 16;
      const float* r = accR[a][c];

      float q0 = r[0] * r[0];
      float q1 = r[1] * r[1] + r[2] * r[2] + r[3] * r[3];
      float q2 = r[4] * r[4] + r[5] * r[5] + r[6] * r[6];
      float q3 = r[7] * r[7];
      float nrm[4];
      nrm[0] = sqrtf(sqrtf(q0 * q0 + 1e-16f));
      nrm[1] = sqrtf(sqrtf(q1 * q1 + 1e-16f));
      nrm[2] = sqrtf(sqrtf(q2 * q2 + 1e-16f));
      nrm[3] = sqrtf(sqrtf(q3 * q3 + 1e-16f));
      float invn[4];
      #pragma unroll
      for (int g = 0; g < 4; ++g)
        invn[g] = 1.0f / (sg[g] * (nrm[g] - 1.0f) + 1.0f + 1e-6f);

      float xr[8];
      #pragma unroll
      for (int i = 0; i < 8; ++i) xr[i] = r[i] * invn[T.gr[i]];

      f8 xv = ld8(x + (((size_t)b) * Fsz + n) * 8);

      float gp[8] = {0, 0, 0, 0, 0, 0, 0, 0};
      #pragma unroll
      for (int i = 0; i < 8; ++i) {
        #pragma unroll
        for (int k = 0; k < 8; ++k) {
          const int p = i * 8 + k;
          gp[T.jidx[p]] += T.sgn[p] * wd[T.path[p]] * xv.v[i] * xr[k];
        }
      }

      float o[8];
      #pragma unroll
      for (int i = 0; i < 8; ++i)
        o[i] = (accL[a][c][i] + gp[i] + (i == 0 ? bias : 0.f)) * inv_sqrt2;

      float4* dst = (float4*)(out + (((size_t)b) * Fsz + n) * 8);
      dst[0] = make_float4(o[0], o[1], o[2], o[3]);
      dst[1] = make_float4(o[4], o[5], o[6], o[7]);
    }
  }
}

}  // namespace

extern "C" void kernel_launch(void* const* d_in, const int* in_sizes, int n_in,
                              void* d_out, int out_size, void* d_ws, size_t ws_size,
                              hipStream_t stream) {
  const float* x   = (const float*)d_in[0];
  const float* wl  = (const float*)d_in[1];
  const float* bl  = (const float*)d_in[2];
  const float* wr  = (const float*)d_in[3];
  const float* an  = (const float*)d_in[4];
  const float* wgp = (const float*)d_in[5];
  float* out = (float*)d_out;

  // workspace layout (ushort elements): xhf [8][8192][256], whf [8][256][256]
  const size_t NXE = (size_t)8 * Bsz * Fsz;      // 16,777,216
  const size_t NWE = (size_t)8 * Fsz * Fsz;      //    524,288
  const size_t need = (NXE + NWE) * sizeof(unsigned short);  // 34,603,008 B

  if (d_ws != nullptr && ws_size >= need) {
    unsigned short* xhf = (unsigned short*)d_ws;
    unsigned short* whf = xhf + NXE;

    prep_all<<<dim3(1536), dim3(256), 0, stream>>>(x, wl, wr, xhf, whf);
    sgp_mfma<<<dim3(1024), dim3(512), 0, stream>>>(
        x, bl, an, wgp, xhf, whf, out);
  } else {
    // fallback: verified fp32 VALU kernel
    dim3 grid(Bsz / BT, Fsz / NT);
    sgp_fused<<<grid, dim3(256), 0, stream>>>(x, wl, bl, wr, an, wgp, out);
  }
}